// Round 8
// baseline (848.637 us; speedup 1.0000x reference)
//
#include <hip/hip_runtime.h>

#define N_USERS 50000
#define NN0 200000
#define NN1 50000
#define NN2 12500
#define EE0 1600000
#define EE1 400000
#define EE2 100000

// Padded segment geometry for fused CSR builds (padded to 1024 multiples):
// seg:      0:e0        1:e1      2:e2      3:parent1  4:parent2
// deg off:  0           200704    250880    264192     314368   (total 327680)
// scan blk: 196         49        13        49         13       (cum 196,245,258,307,320)
// bsum off: 0           196       245       258        307
// el off:   0           1600000   2000000   2100000    2300000

// ---------------- encoder: h128[r] = leaky([d|t|n|c]), reg-prefetch pipeline --
__global__ __launch_bounds__(256) void k_enc3(
    const float* __restrict__ xr,
    const float* __restrict__ Wd, const float* __restrict__ bd,
    const float* __restrict__ Wt, const float* __restrict__ bt,
    const float* __restrict__ Wn, const float* __restrict__ bn,
    const float* __restrict__ Wc, const float* __restrict__ bc,
    float* __restrict__ h128)
{
    __shared__ float XsD[32][68];  // [k][row] des chunk (transposed)
    __shared__ float XsT[32][68];  // [k][row] tweet chunk
    __shared__ float Ws[32][68];   // [k][col 0..63] = [Wd|Wt]
    __shared__ float xnc[64][8];
    __shared__ float Wl[8][64];

    int t = threadIdx.x;
    int cg = t & 15, rg = t >> 4;
    int base = blockIdx.x * 64;

    if (t < 64) {
        int row = base + t;
        if (row < N_USERS) {
            const float* xp = xr + (size_t)row * 1544;
            float4 a = *(const float4*)xp;
            float2 b2 = *(const float2*)(xp + 4);
            float2 c2 = *(const float2*)(xp + 774);
            xnc[t][0] = a.x; xnc[t][1] = a.y; xnc[t][2] = a.z; xnc[t][3] = a.w;
            xnc[t][4] = b2.x; xnc[t][5] = b2.y; xnc[t][6] = c2.x; xnc[t][7] = c2.y;
        } else {
            #pragma unroll
            for (int k = 0; k < 8; k++) xnc[t][k] = 0.f;
        }
    } else if (t >= 192) {
        int l = t - 192;
        #pragma unroll
        for (int k = 0; k < 8; k++) {
            float w = 0.f;
            if (l < 32) { if (k < 6) w = Wn[k * 32 + l]; }
            else        { if (k >= 6) w = Wc[(k - 6) * 32 + (l - 32)]; }
            Wl[k][l] = w;
        }
    }

    int srow[2], sq[2];
    #pragma unroll
    for (int h = 0; h < 2; h++) { int fi = t * 2 + h; srow[h] = fi >> 3; sq[h] = fi & 7; }
    bool vr[2];
    #pragma unroll
    for (int h = 0; h < 2; h++) vr[h] = (base + srow[h]) < N_USERS;

    float4 pvd[2]; float2 pva[2], pvb[2]; float4 pw[2];

    // prologue: load chunk 0
    #pragma unroll
    for (int h = 0; h < 2; h++) {
        pvd[h] = make_float4(0.f, 0.f, 0.f, 0.f);
        pva[h] = make_float2(0.f, 0.f); pvb[h] = make_float2(0.f, 0.f);
        if (vr[h]) {
            const float* xp = xr + (size_t)(base + srow[h]) * 1544 + sq[h] * 4;
            pvd[h] = *(const float4*)(xp + 776);
            pva[h] = *(const float2*)(xp + 6);
            pvb[h] = *(const float2*)(xp + 8);
        }
        int fi = t + h * 256;
        int k = fi >> 4, c4 = (fi & 15) * 4;
        pw[h] = (c4 < 32) ? *(const float4*)(Wd + (size_t)k * 32 + c4)
                          : *(const float4*)(Wt + (size_t)k * 32 + (c4 - 32));
    }

    float acc[4][4];
    #pragma unroll
    for (int r = 0; r < 4; r++)
        #pragma unroll
        for (int c = 0; c < 4; c++) acc[r][c] = 0.f;

    for (int kc = 0; kc < 768; kc += 32) {
        __syncthreads();
        // write staged regs to LDS
        #pragma unroll
        for (int h = 0; h < 2; h++) {
            int k0 = sq[h] * 4, row = srow[h];
            XsD[k0 + 0][row] = pvd[h].x; XsD[k0 + 1][row] = pvd[h].y;
            XsD[k0 + 2][row] = pvd[h].z; XsD[k0 + 3][row] = pvd[h].w;
            XsT[k0 + 0][row] = pva[h].x; XsT[k0 + 1][row] = pva[h].y;
            XsT[k0 + 2][row] = pvb[h].x; XsT[k0 + 3][row] = pvb[h].y;
            int fi = t + h * 256;
            int k = fi >> 4, c4 = (fi & 15) * 4;
            *(float4*)&Ws[k][c4] = pw[h];
        }
        __syncthreads();
        // prefetch next chunk (latency hides under compute)
        int kn = kc + 32;
        if (kn < 768) {
            #pragma unroll
            for (int h = 0; h < 2; h++) {
                if (vr[h]) {
                    const float* xp = xr + (size_t)(base + srow[h]) * 1544 + kn + sq[h] * 4;
                    pvd[h] = *(const float4*)(xp + 776);
                    pva[h] = *(const float2*)(xp + 6);
                    pvb[h] = *(const float2*)(xp + 8);
                }
                int fi = t + h * 256;
                int k = fi >> 4, c4 = (fi & 15) * 4;
                pw[h] = (c4 < 32) ? *(const float4*)(Wd + (size_t)(kn + k) * 32 + c4)
                                  : *(const float4*)(Wt + (size_t)(kn + k) * 32 + (c4 - 32));
            }
        }

        const float* Xp = (cg < 8) ? &XsD[0][0] : &XsT[0][0];
        #pragma unroll 8
        for (int k = 0; k < 32; k++) {
            float4 xv = *(const float4*)(Xp + k * 68 + rg * 4);
            float4 wv = *(const float4*)&Ws[k][cg * 4];
            acc[0][0] = fmaf(xv.x, wv.x, acc[0][0]);
            acc[0][1] = fmaf(xv.x, wv.y, acc[0][1]);
            acc[0][2] = fmaf(xv.x, wv.z, acc[0][2]);
            acc[0][3] = fmaf(xv.x, wv.w, acc[0][3]);
            acc[1][0] = fmaf(xv.y, wv.x, acc[1][0]);
            acc[1][1] = fmaf(xv.y, wv.y, acc[1][1]);
            acc[1][2] = fmaf(xv.y, wv.z, acc[1][2]);
            acc[1][3] = fmaf(xv.y, wv.w, acc[1][3]);
            acc[2][0] = fmaf(xv.z, wv.x, acc[2][0]);
            acc[2][1] = fmaf(xv.z, wv.y, acc[2][1]);
            acc[2][2] = fmaf(xv.z, wv.z, acc[2][2]);
            acc[2][3] = fmaf(xv.z, wv.w, acc[2][3]);
            acc[3][0] = fmaf(xv.w, wv.x, acc[3][0]);
            acc[3][1] = fmaf(xv.w, wv.y, acc[3][1]);
            acc[3][2] = fmaf(xv.w, wv.z, acc[3][2]);
            acc[3][3] = fmaf(xv.w, wv.w, acc[3][3]);
        }
    }

    float bh[4], bl[4], wlv[8][4];
    #pragma unroll
    for (int c = 0; c < 4; c++) {
        int j = cg * 4 + c;
        bh[c] = (j < 32) ? bd[j] : bt[j - 32];
        bl[c] = (j < 32) ? bn[j] : bc[j - 32];
        #pragma unroll
        for (int k = 0; k < 8; k++) wlv[k][c] = Wl[k][j];
    }
    #pragma unroll
    for (int r = 0; r < 4; r++) {
        int lr = rg * 4 + r;
        int row = base + lr;
        if (row >= N_USERS) break;
        float4 hv;
        float* ph = &hv.x;
        #pragma unroll
        for (int c = 0; c < 4; c++) {
            float v = acc[r][c] + bh[c];
            ph[c] = v > 0.f ? v : 0.01f * v;
        }
        *(float4*)(h128 + (size_t)row * 128 + cg * 4) = hv;
        float4 lv;
        float* pl = &lv.x;
        #pragma unroll
        for (int c = 0; c < 4; c++) {
            float v = bl[c];
            #pragma unroll
            for (int k = 0; k < 8; k++) v = fmaf(xnc[lr][k], wlv[k][c], v);
            pl[c] = v > 0.f ? v : 0.01f * v;
        }
        *(float4*)(h128 + (size_t)row * 128 + 64 + cg * 4) = lv;
    }
}

// ---------------- fused dual GEMM: U = (prelu(X@W1+b1)) @ W2 -----------------
__global__ __launch_bounds__(256) void k_gemm2(
    const float* __restrict__ X, const float* __restrict__ W1,
    const float* __restrict__ b1, const float* __restrict__ pa,
    const float* __restrict__ W2, float* __restrict__ OUT, int n)
{
    __shared__ float Xs[32][132];
    __shared__ float Ws[32][132];
    int t = threadIdx.x;
    int cg = t & 31, rg = t >> 5;
    int base = blockIdx.x * 32;

    #pragma unroll
    for (int h = 0; h < 4; h++) {
        int fi = t + h * 256;
        int row = fi >> 5, q = fi & 31;
        float4 v = {0.f, 0.f, 0.f, 0.f};
        if (base + row < n) v = *(const float4*)(X + (size_t)(base + row) * 128 + q * 4);
        *(float4*)&Xs[row][q * 4] = v;
    }

    float acc[4][4];
    #pragma unroll
    for (int r = 0; r < 4; r++)
        #pragma unroll
        for (int c = 0; c < 4; c++) acc[r][c] = 0.f;

    // pass 1: X@W1
    for (int kc = 0; kc < 128; kc += 32) {
        __syncthreads();
        #pragma unroll
        for (int h = 0; h < 4; h++) {
            int fi = t + h * 256;
            int k = fi >> 5, q = fi & 31;
            *(float4*)&Ws[k][q * 4] = *(const float4*)(W1 + (size_t)(kc + k) * 128 + q * 4);
        }
        __syncthreads();
        #pragma unroll
        for (int k4 = 0; k4 < 8; k4++) {
            int k = k4 * 4;
            float4 w0 = *(const float4*)&Ws[k + 0][cg * 4];
            float4 w1 = *(const float4*)&Ws[k + 1][cg * 4];
            float4 w2 = *(const float4*)&Ws[k + 2][cg * 4];
            float4 w3 = *(const float4*)&Ws[k + 3][cg * 4];
            #pragma unroll
            for (int r = 0; r < 4; r++) {
                float4 xv = *(const float4*)&Xs[rg * 4 + r][kc + k];
                acc[r][0] = fmaf(xv.w, w3.x, fmaf(xv.z, w2.x, fmaf(xv.y, w1.x, fmaf(xv.x, w0.x, acc[r][0]))));
                acc[r][1] = fmaf(xv.w, w3.y, fmaf(xv.z, w2.y, fmaf(xv.y, w1.y, fmaf(xv.x, w0.y, acc[r][1]))));
                acc[r][2] = fmaf(xv.w, w3.z, fmaf(xv.z, w2.z, fmaf(xv.y, w1.z, fmaf(xv.x, w0.z, acc[r][2]))));
                acc[r][3] = fmaf(xv.w, w3.w, fmaf(xv.z, w2.w, fmaf(xv.y, w1.w, fmaf(xv.x, w0.w, acc[r][3]))));
            }
        }
    }

    // prelu epilogue written back into Xs
    float4 bv = *(const float4*)(b1 + cg * 4);
    float4 pv = *(const float4*)(pa + cg * 4);
    __syncthreads();
    #pragma unroll
    for (int r = 0; r < 4; r++) {
        float v0 = acc[r][0] + bv.x; v0 = v0 > 0.f ? v0 : pv.x * v0;
        float v1 = acc[r][1] + bv.y; v1 = v1 > 0.f ? v1 : pv.y * v1;
        float v2 = acc[r][2] + bv.z; v2 = v2 > 0.f ? v2 : pv.z * v2;
        float v3 = acc[r][3] + bv.w; v3 = v3 > 0.f ? v3 : pv.w * v3;
        Xs[rg * 4 + r][cg * 4 + 0] = v0;
        Xs[rg * 4 + r][cg * 4 + 1] = v1;
        Xs[rg * 4 + r][cg * 4 + 2] = v2;
        Xs[rg * 4 + r][cg * 4 + 3] = v3;
        acc[r][0] = 0.f; acc[r][1] = 0.f; acc[r][2] = 0.f; acc[r][3] = 0.f;
    }

    // pass 2: P@W2
    for (int kc = 0; kc < 128; kc += 32) {
        __syncthreads();
        #pragma unroll
        for (int h = 0; h < 4; h++) {
            int fi = t + h * 256;
            int k = fi >> 5, q = fi & 31;
            *(float4*)&Ws[k][q * 4] = *(const float4*)(W2 + (size_t)(kc + k) * 128 + q * 4);
        }
        __syncthreads();
        #pragma unroll
        for (int k4 = 0; k4 < 8; k4++) {
            int k = k4 * 4;
            float4 w0 = *(const float4*)&Ws[k + 0][cg * 4];
            float4 w1 = *(const float4*)&Ws[k + 1][cg * 4];
            float4 w2 = *(const float4*)&Ws[k + 2][cg * 4];
            float4 w3 = *(const float4*)&Ws[k + 3][cg * 4];
            #pragma unroll
            for (int r = 0; r < 4; r++) {
                float4 xv = *(const float4*)&Xs[rg * 4 + r][kc + k];
                acc[r][0] = fmaf(xv.w, w3.x, fmaf(xv.z, w2.x, fmaf(xv.y, w1.x, fmaf(xv.x, w0.x, acc[r][0]))));
                acc[r][1] = fmaf(xv.w, w3.y, fmaf(xv.z, w2.y, fmaf(xv.y, w1.y, fmaf(xv.x, w0.y, acc[r][1]))));
                acc[r][2] = fmaf(xv.w, w3.z, fmaf(xv.z, w2.z, fmaf(xv.y, w1.z, fmaf(xv.x, w0.z, acc[r][2]))));
                acc[r][3] = fmaf(xv.w, w3.w, fmaf(xv.z, w2.w, fmaf(xv.y, w1.w, fmaf(xv.x, w0.w, acc[r][3]))));
            }
        }
    }

    #pragma unroll
    for (int r = 0; r < 4; r++) {
        int row = base + rg * 4 + r;
        if (row >= n) break;
        float4 v;
        v.x = acc[r][0]; v.y = acc[r][1]; v.z = acc[r][2]; v.w = acc[r][3];
        *(float4*)(OUT + (size_t)row * 128 + cg * 4) = v;
    }
}

// ---------------- [n,128] @ [128,128] GEMM, 4x4 register tile ----------------
__global__ __launch_bounds__(256) void k_gemmT(
    const float* X, const float* __restrict__ W, float* OUT, int n)
{
    __shared__ float Xs[32][132];
    __shared__ float Ws[32][132];
    int t = threadIdx.x;
    int cg = t & 31, rg = t >> 5;
    int base = blockIdx.x * 32;

    #pragma unroll
    for (int h = 0; h < 4; h++) {
        int fi = t + h * 256;
        int row = fi >> 5, q = fi & 31;
        float4 v = {0.f, 0.f, 0.f, 0.f};
        if (base + row < n) v = *(const float4*)(X + (size_t)(base + row) * 128 + q * 4);
        *(float4*)&Xs[row][q * 4] = v;
    }

    float acc[4][4];
    #pragma unroll
    for (int r = 0; r < 4; r++)
        #pragma unroll
        for (int c = 0; c < 4; c++) acc[r][c] = 0.f;

    for (int kc = 0; kc < 128; kc += 32) {
        __syncthreads();
        #pragma unroll
        for (int h = 0; h < 4; h++) {
            int fi = t + h * 256;
            int k = fi >> 5, q = fi & 31;
            *(float4*)&Ws[k][q * 4] = *(const float4*)(W + (size_t)(kc + k) * 128 + q * 4);
        }
        __syncthreads();
        #pragma unroll
        for (int k4 = 0; k4 < 8; k4++) {
            int k = k4 * 4;
            float4 w0 = *(const float4*)&Ws[k + 0][cg * 4];
            float4 w1 = *(const float4*)&Ws[k + 1][cg * 4];
            float4 w2 = *(const float4*)&Ws[k + 2][cg * 4];
            float4 w3 = *(const float4*)&Ws[k + 3][cg * 4];
            #pragma unroll
            for (int r = 0; r < 4; r++) {
                float4 xv = *(const float4*)&Xs[rg * 4 + r][kc + k];
                acc[r][0] = fmaf(xv.w, w3.x, fmaf(xv.z, w2.x, fmaf(xv.y, w1.x, fmaf(xv.x, w0.x, acc[r][0]))));
                acc[r][1] = fmaf(xv.w, w3.y, fmaf(xv.z, w2.y, fmaf(xv.y, w1.y, fmaf(xv.x, w0.y, acc[r][1]))));
                acc[r][2] = fmaf(xv.w, w3.z, fmaf(xv.z, w2.z, fmaf(xv.y, w1.z, fmaf(xv.x, w0.z, acc[r][2]))));
                acc[r][3] = fmaf(xv.w, w3.w, fmaf(xv.z, w2.w, fmaf(xv.y, w1.w, fmaf(xv.x, w0.w, acc[r][3]))));
            }
        }
    }

    #pragma unroll
    for (int r = 0; r < 4; r++) {
        int row = base + rg * 4 + r;
        if (row >= n) break;
        float4 v;
        v.x = acc[r][0]; v.y = acc[r][1]; v.z = acc[r][2]; v.w = acc[r][3];
        *(float4*)(OUT + (size_t)row * 128 + cg * 4) = v;
    }
}

// ---------------- fused CSR build over 5 segments ----------------------------
__device__ __forceinline__ void seg_of_scanblk(int b, int& doff, int& bsoff, int& lb) {
    if (b < 196)      { doff = 0;      bsoff = 0;   lb = b; }
    else if (b < 245) { doff = 200704; bsoff = 196; lb = b - 196; }
    else if (b < 258) { doff = 250880; bsoff = 245; lb = b - 245; }
    else if (b < 307) { doff = 264192; bsoff = 258; lb = b - 258; }
    else              { doff = 314368; bsoff = 307; lb = b - 307; }
}

__global__ __launch_bounds__(256) void k_count_all(
    const int* __restrict__ d0, const int* __restrict__ d1, const int* __restrict__ d2,
    const int* __restrict__ p1, const int* __restrict__ p2,
    int* __restrict__ degs, int* __restrict__ ranks)
{
    int t0 = blockIdx.x * 256 + threadIdx.x;
    if (t0 >= 587500) return;
    #pragma unroll
    for (int k = 0; k < 4; k++) {
        int gid = t0 + k * 587500;
        int idx;
        if (gid < 1600000)      idx = d0[gid];
        else if (gid < 2000000) idx = 200704 + d1[gid - 1600000];
        else if (gid < 2100000) idx = 250880 + d2[gid - 2000000];
        else if (gid < 2300000) idx = 264192 + p1[gid - 2100000];
        else                    idx = 314368 + p2[gid - 2300000];
        ranks[gid] = atomicAdd(&degs[idx], 1);
    }
}

__global__ __launch_bounds__(256) void k_scan_all(
    const int* __restrict__ degs, int* __restrict__ rowsts, int* __restrict__ bsums)
{
    __shared__ int sh[256];
    int doff, bsoff, lb;
    seg_of_scanblk(blockIdx.x, doff, bsoff, lb);
    int t = threadIdx.x;
    int base = doff + lb * 1024 + t * 4;
    int v[4], s = 0;
    #pragma unroll
    for (int k = 0; k < 4; k++) { v[k] = degs[base + k]; s += v[k]; }
    sh[t] = s;
    __syncthreads();
    for (int off = 1; off < 256; off <<= 1) {
        int x = 0;
        if (t >= off) x = sh[t - off];
        __syncthreads();
        if (t >= off) sh[t] += x;
        __syncthreads();
    }
    int ex = sh[t] - s;
    if (t == 255) bsums[bsoff + lb] = sh[255];
    #pragma unroll
    for (int k = 0; k < 4; k++) { rowsts[base + k] = ex; ex += v[k]; }
}

// add block offsets (self-computed prefix of raw bsums) + dinv for segs 0-2
__global__ __launch_bounds__(256) void k_scanadd_all(
    int* __restrict__ rowsts, const int* __restrict__ bsums,
    const int* __restrict__ degs, float* __restrict__ dinvs)
{
    __shared__ int sh[256];
    int doff, bsoff, lb;
    seg_of_scanblk(blockIdx.x, doff, bsoff, lb);
    int t = threadIdx.x;
    sh[t] = (t < lb) ? bsums[bsoff + t] : 0;
    __syncthreads();
    #pragma unroll
    for (int off = 128; off >= 1; off >>= 1) {
        if (t < off) sh[t] += sh[t + off];
        __syncthreads();
    }
    int add = sh[0];
    int base = doff + lb * 1024 + t * 4;
    bool dodinv = (doff <= 250880);
    #pragma unroll
    for (int k = 0; k < 4; k++) {
        int i = base + k;
        rowsts[i] += add;
        if (dodinv) dinvs[i] = rsqrtf((float)degs[i] + 1.0f);
    }
}

// atomic-free scatter: p = rowsts[key] + rank[e]
__global__ __launch_bounds__(256) void k_scatter_all(
    const int* __restrict__ s0, const int* __restrict__ d0,
    const int* __restrict__ s1, const int* __restrict__ d1,
    const int* __restrict__ s2, const int* __restrict__ d2,
    const int* __restrict__ p1, const int* __restrict__ p2,
    const int* __restrict__ rowsts, const int* __restrict__ ranks,
    int* __restrict__ elists)
{
    int t0 = blockIdx.x * 256 + threadIdx.x;
    if (t0 >= 587500) return;
    #pragma unroll
    for (int k = 0; k < 4; k++) {
        int gid = t0 + k * 587500;
        int idx, val, eloff;
        if (gid < 1600000)      { idx = d0[gid];                    val = s0[gid];           eloff = 0; }
        else if (gid < 2000000) { int i = gid - 1600000; idx = 200704 + d1[i]; val = s1[i]; eloff = 1600000; }
        else if (gid < 2100000) { int i = gid - 2000000; idx = 250880 + d2[i]; val = s2[i]; eloff = 2000000; }
        else if (gid < 2300000) { int i = gid - 2100000; idx = 264192 + p1[i]; val = i;     eloff = 2100000; }
        else                    { int i = gid - 2300000; idx = 314368 + p2[i]; val = i;     eloff = 2300000; }
        int p = rowsts[idx] + ranks[gid];
        elists[eloff + p] = val;
    }
}

// ---------------- fused GCN + SE-pool ----------------------------------------
// out[p] = relu( sum_{d in children(p)} relu((U[nl[d]]*dd + sum_s U[nl[s]]*ds)*dd + b) )
__global__ __launch_bounds__(256) void k_gcnpoolU(
    const float* __restrict__ U, const int* __restrict__ nl,
    const int* __restrict__ rowstE, const int* __restrict__ elistE,
    const float* __restrict__ dinv, const float* __restrict__ bias,
    const int* __restrict__ prowst, const int* __restrict__ pelist,
    float* __restrict__ out, int np)
{
    size_t gid = (size_t)blockIdx.x * 256 + threadIdx.x;
    int p = (int)(gid >> 5);
    if (p >= np) return;
    int l = (int)(gid & 31);
    const float4* Uv = (const float4*)U;
    const float4 b = ((const float4*)bias)[l];
    float4 acc = {0.f, 0.f, 0.f, 0.f};
    int c0 = prowst[p], c1 = prowst[p + 1];
    for (int c = c0; c < c1; ++c) {
        int d = pelist[c];
        float dd = dinv[d];
        float4 self = Uv[(size_t)nl[d] * 32 + l];
        float4 a;
        a.x = self.x * dd; a.y = self.y * dd; a.z = self.z * dd; a.w = self.w * dd;
        int e0 = rowstE[d], e1 = rowstE[d + 1];
        for (int e = e0; e < e1; ++e) {
            int s = elistE[e];
            float ds = dinv[s];
            float4 v = Uv[(size_t)nl[s] * 32 + l];
            a.x = fmaf(v.x, ds, a.x); a.y = fmaf(v.y, ds, a.y);
            a.z = fmaf(v.z, ds, a.z); a.w = fmaf(v.w, ds, a.w);
        }
        acc.x += fmaxf(fmaf(a.x, dd, b.x), 0.f);
        acc.y += fmaxf(fmaf(a.y, dd, b.y), 0.f);
        acc.z += fmaxf(fmaf(a.z, dd, b.z), 0.f);
        acc.w += fmaxf(fmaf(a.w, dd, b.w), 0.f);
    }
    float4 y;
    y.x = fmaxf(acc.x, 0.f); y.y = fmaxf(acc.y, 0.f);
    y.z = fmaxf(acc.z, 0.f); y.w = fmaxf(acc.w, 0.f);
    ((float4*)out)[(size_t)p * 32 + l] = y;
}

// same, direct h rows (no nodelist indirection)
__global__ __launch_bounds__(256) void k_gcnpool(
    const float* __restrict__ h,
    const int* __restrict__ rowstE, const int* __restrict__ elistE,
    const float* __restrict__ dinv, const float* __restrict__ bias,
    const int* __restrict__ prowst, const int* __restrict__ pelist,
    float* __restrict__ out, int np)
{
    size_t gid = (size_t)blockIdx.x * 256 + threadIdx.x;
    int p = (int)(gid >> 5);
    if (p >= np) return;
    int l = (int)(gid & 31);
    const float4* hv = (const float4*)h;
    const float4 b = ((const float4*)bias)[l];
    float4 acc = {0.f, 0.f, 0.f, 0.f};
    int c0 = prowst[p], c1 = prowst[p + 1];
    for (int c = c0; c < c1; ++c) {
        int d = pelist[c];
        float dd = dinv[d];
        float4 self = hv[(size_t)d * 32 + l];
        float4 a;
        a.x = self.x * dd; a.y = self.y * dd; a.z = self.z * dd; a.w = self.w * dd;
        int e0 = rowstE[d], e1 = rowstE[d + 1];
        for (int e = e0; e < e1; ++e) {
            int s = elistE[e];
            float ds = dinv[s];
            float4 v = hv[(size_t)s * 32 + l];
            a.x = fmaf(v.x, ds, a.x); a.y = fmaf(v.y, ds, a.y);
            a.z = fmaf(v.z, ds, a.z); a.w = fmaf(v.w, ds, a.w);
        }
        acc.x += fmaxf(fmaf(a.x, dd, b.x), 0.f);
        acc.y += fmaxf(fmaf(a.y, dd, b.y), 0.f);
        acc.z += fmaxf(fmaf(a.z, dd, b.z), 0.f);
        acc.w += fmaxf(fmaf(a.w, dd, b.w), 0.f);
    }
    float4 y;
    y.x = fmaxf(acc.x, 0.f); y.y = fmaxf(acc.y, 0.f);
    y.z = fmaxf(acc.z, 0.f); y.w = fmaxf(acc.w, 0.f);
    ((float4*)out)[(size_t)p * 32 + l] = y;
}

// plain GCN layer (L2, no pool): out[d] = relu((h[d]*dd + sum h[s]*ds)*dd + b)
__global__ __launch_bounds__(256) void k_gather(
    const float* __restrict__ h, const int* __restrict__ rowst,
    const int* __restrict__ elist, const float* __restrict__ dinv,
    const float* __restrict__ bias, float* __restrict__ out, int n)
{
    size_t gid = (size_t)blockIdx.x * 256 + threadIdx.x;
    int d = (int)(gid >> 5);
    if (d >= n) return;
    int l = (int)(gid & 31);
    const float4* hv = (const float4*)h;
    float dd = dinv[d];
    float4 self = hv[(size_t)d * 32 + l];
    float4 acc;
    acc.x = self.x * dd; acc.y = self.y * dd; acc.z = self.z * dd; acc.w = self.w * dd;
    int s0 = rowst[d], s1 = rowst[d + 1];
    for (int e = s0; e < s1; ++e) {
        int s = elist[e];
        float ds = dinv[s];
        float4 v = hv[(size_t)s * 32 + l];
        acc.x = fmaf(v.x, ds, acc.x);
        acc.y = fmaf(v.y, ds, acc.y);
        acc.z = fmaf(v.z, ds, acc.z);
        acc.w = fmaf(v.w, ds, acc.w);
    }
    const float4 b = ((const float4*)bias)[l];
    float4 y;
    y.x = fmaxf(fmaf(acc.x, dd, b.x), 0.f);
    y.y = fmaxf(fmaf(acc.y, dd, b.y), 0.f);
    y.z = fmaxf(fmaf(acc.z, dd, b.z), 0.f);
    y.w = fmaxf(fmaf(acc.w, dd, b.w), 0.f);
    ((float4*)out)[(size_t)d * 32 + l] = y;
}

__global__ __launch_bounds__(128) void k_bpool_all(
    const float* __restrict__ X1, const float* __restrict__ X2, const float* __restrict__ Y2,
    const int* __restrict__ b1, const int* __restrict__ b2, float* __restrict__ pl)
{
    int b = blockIdx.x;
    const float* src; const int* bidx; int coloff, n, r0;
    if (b < 391)      { src = X1; bidx = b1; coloff = 0;   n = 50000; r0 = b * 128; }
    else if (b < 489) { src = X2; bidx = b2; coloff = 128; n = 12500; r0 = (b - 391) * 128; }
    else              { src = Y2; bidx = b2; coloff = 256; n = 12500; r0 = (b - 489) * 128; }
    if (r0 >= n) return;
    int j = threadIdx.x;
    int r1 = min(r0 + 128, n);
    float acc = 0.f;
    int prev = bidx[r0];
    for (int r = r0; r < r1; ++r) {
        int bb = bidx[r];
        if (bb != prev) {
            unsafeAtomicAdd(&pl[(size_t)prev * 384 + coloff + j], acc);
            acc = 0.f; prev = bb;
        }
        acc += src[(size_t)r * 128 + j];
    }
    unsafeAtomicAdd(&pl[(size_t)prev * 384 + coloff + j], acc);
}

// fused 2-layer MLP: out[r] = (relu(PL[r]@Wc1+bc1))@Wc2+bc2
__global__ void k_mlp2(const float* __restrict__ PL,
                       const float* __restrict__ Wc1, const float* __restrict__ bc1,
                       const float* __restrict__ Wc2, const float* __restrict__ bc2,
                       float* __restrict__ out)
{
    __shared__ float as[384];
    __shared__ float zs[128];
    int r = blockIdx.x, j = threadIdx.x;
    as[j] = PL[(size_t)r * 384 + j];
    as[j + 128] = PL[(size_t)r * 384 + 128 + j];
    as[j + 256] = PL[(size_t)r * 384 + 256 + j];
    __syncthreads();
    float acc = bc1[j];
    for (int k = 0; k < 384; k++) acc = fmaf(as[k], Wc1[(size_t)k * 128 + j], acc);
    zs[j] = fmaxf(acc, 0.f);
    __syncthreads();
    float o = bc2[j];
    for (int k = 0; k < 128; k++) o = fmaf(zs[k], Wc2[(size_t)k * 128 + j], o);
    out[(size_t)r * 128 + j] = o;
}

extern "C" void kernel_launch(void* const* d_in, const int* in_sizes, int n_in,
                              void* d_out, int out_size, void* d_ws, size_t ws_size,
                              hipStream_t stream)
{
    const float* x_raw  = (const float*)d_in[0];
    const float* W_des  = (const float*)d_in[1];
    const float* b_des  = (const float*)d_in[2];
    const float* W_twe  = (const float*)d_in[3];
    const float* b_twe  = (const float*)d_in[4];
    const float* W_num  = (const float*)d_in[5];
    const float* b_num  = (const float*)d_in[6];
    const float* W_cat  = (const float*)d_in[7];
    const float* b_cat  = (const float*)d_in[8];
    const float* W_in   = (const float*)d_in[9];
    const float* b_in   = (const float*)d_in[10];
    const float* prelua = (const float*)d_in[11];
    const float* W_conv = (const float*)d_in[12];
    const float* b_conv = (const float*)d_in[13];
    const float* Wc1    = (const float*)d_in[14];
    const float* bc1    = (const float*)d_in[15];
    const float* Wc2    = (const float*)d_in[16];
    const float* bc2    = (const float*)d_in[17];
    const int* nodelist = (const int*)d_in[18];
    const int* e0       = (const int*)d_in[19];
    const int* e1       = (const int*)d_in[20];
    const int* e2       = (const int*)d_in[21];
    const int* parent1  = (const int*)d_in[22];
    const int* parent2  = (const int*)d_in[23];
    const int* batch1   = (const int*)d_in[24];
    const int* batch2   = (const int*)d_in[25];

    // ---- workspace layout ----
    float* WS  = (float*)d_ws;
    float* ENC = WS;                    // 50000*128; dead after k_gemm2
    // CSR scratch aliases ENC (built after k_gemm2): 22.5 MB < 25.6 MB
    int*   DEGS   = (int*)d_ws;                 // 327680
    int*   ROWSTS = DEGS + 327680;              // 327680
    float* DINVS  = (float*)(ROWSTS + 327680);  // 264192
    int*   BSUMS  = (int*)(DINVS + 264192);     // 512
    int*   RANKS  = BSUMS + 512;                // 2350000
    int*   ELISTS = RANKS + 2350000;            // 2350000
    float* U  = WS + 6400000;           // 50000*128
    float* H  = WS + 12800000;          // 50000*128 (L1/L2 lin outputs)
    float* Y  = WS + 19200000;          // L2 gcn out (12500*128)
    float* X1 = WS + 44800000;          // 50000*128
    float* X2 = WS + 51200000;          // 12500*128
    float* PL = WS + 52800000;          // 128*384
    // Z no longer needed (mlp fused)

    hipMemsetAsync(PL, 0, (size_t)128 * 384 * 4, stream);

    // ---- encoder -> ENC; U = prelu(ENC@W_in+b)@W_conv0 (fused) ----
    k_enc3<<<(N_USERS + 63) / 64, 256, 0, stream>>>(
        x_raw, W_des, b_des, W_twe, b_twe, W_num, b_num, W_cat, b_cat, ENC);
    k_gemm2<<<(N_USERS + 31) / 32, 256, 0, stream>>>(
        ENC, W_in, b_in, prelua, W_conv, U, N_USERS);

    // ---- fused CSR builds (+dinv); clobbers ENC (dead) ----
    hipMemsetAsync(DEGS, 0, (size_t)327680 * 4, stream);
    k_count_all<<<(587500 + 255) / 256, 256, 0, stream>>>(
        e0 + EE0, e1 + EE1, e2 + EE2, parent1, parent2, DEGS, RANKS);
    k_scan_all<<<320, 256, 0, stream>>>(DEGS, ROWSTS, BSUMS);
    k_scanadd_all<<<320, 256, 0, stream>>>(ROWSTS, BSUMS, DEGS, DINVS);
    k_scatter_all<<<(587500 + 255) / 256, 256, 0, stream>>>(
        e0, e0 + EE0, e1, e1 + EE1, e2, e2 + EE2, parent1, parent2,
        ROWSTS, RANKS, ELISTS);

    // ---- layer 0: fused GCN + pool -> X1 ----
    k_gcnpoolU<<<(int)(((size_t)NN1 * 32 + 255) / 256), 256, 0, stream>>>(
        U, nodelist, ROWSTS, ELISTS, DINVS, b_conv,
        ROWSTS + 264192, ELISTS + 2100000, X1, NN1);

    // ---- layer 1: lin + fused GCN + pool -> X2 ----
    k_gemmT<<<(NN1 + 31) / 32, 256, 0, stream>>>(X1, W_conv + 16384, H, NN1);
    k_gcnpool<<<(int)(((size_t)NN2 * 32 + 255) / 256), 256, 0, stream>>>(
        H, ROWSTS + 200704, ELISTS + 1600000, DINVS + 200704, b_conv + 128,
        ROWSTS + 314368, ELISTS + 2300000, X2, NN2);

    // ---- layer 2: lin + GCN -> Y ----
    k_gemmT<<<(NN2 + 31) / 32, 256, 0, stream>>>(X2, W_conv + 32768, H, NN2);
    k_gather<<<(int)(((size_t)NN2 * 32 + 255) / 256), 256, 0, stream>>>(
        H, ROWSTS + 250880, ELISTS + 2000000, DINVS + 250880, b_conv + 256, Y, NN2);

    // ---- batch pooling (fused, sorted keys) ----
    k_bpool_all<<<587, 128, 0, stream>>>(X1, X2, Y, batch1, batch2, PL);

    // ---- final fused MLP ----
    k_mlp2<<<128, 128, 0, stream>>>(PL, Wc1, bc1, Wc2, bc2, (float*)d_out);
}

// Round 9
// 792.509 us; speedup vs baseline: 1.0708x; 1.0708x over previous
//
#include <hip/hip_runtime.h>

#define N_USERS 50000
#define NN0 200000
#define NN1 50000
#define NN2 12500
#define EE0 1600000
#define EE1 400000
#define EE2 100000

// Padded segment geometry for fused CSR builds (padded to 1024 multiples):
// seg:      0:e0        1:e1      2:e2      3:parent1  4:parent2
// deg off:  0           200704    250880    264192     314368   (total 327680)
// scan blk: 196         49        13        49         13       (cum 196,245,258,307,320)
// bsum off: 0           196       245       258        307
// el off:   0           1600000   2000000   2100000    2300000

// ---------------- encoder: h128[r] = leaky([d|t|n|c]), reg-prefetch pipeline --
__global__ __launch_bounds__(256) void k_enc3(
    const float* __restrict__ xr,
    const float* __restrict__ Wd, const float* __restrict__ bd,
    const float* __restrict__ Wt, const float* __restrict__ bt,
    const float* __restrict__ Wn, const float* __restrict__ bn,
    const float* __restrict__ Wc, const float* __restrict__ bc,
    float* __restrict__ h128)
{
    __shared__ float XsD[32][68];
    __shared__ float XsT[32][68];
    __shared__ float Ws[32][68];
    __shared__ float xnc[64][8];
    __shared__ float Wl[8][64];

    int t = threadIdx.x;
    int cg = t & 15, rg = t >> 4;
    int base = blockIdx.x * 64;

    if (t < 64) {
        int row = base + t;
        if (row < N_USERS) {
            const float* xp = xr + (size_t)row * 1544;
            float4 a = *(const float4*)xp;
            float2 b2 = *(const float2*)(xp + 4);
            float2 c2 = *(const float2*)(xp + 774);
            xnc[t][0] = a.x; xnc[t][1] = a.y; xnc[t][2] = a.z; xnc[t][3] = a.w;
            xnc[t][4] = b2.x; xnc[t][5] = b2.y; xnc[t][6] = c2.x; xnc[t][7] = c2.y;
        } else {
            #pragma unroll
            for (int k = 0; k < 8; k++) xnc[t][k] = 0.f;
        }
    } else if (t >= 192) {
        int l = t - 192;
        #pragma unroll
        for (int k = 0; k < 8; k++) {
            float w = 0.f;
            if (l < 32) { if (k < 6) w = Wn[k * 32 + l]; }
            else        { if (k >= 6) w = Wc[(k - 6) * 32 + (l - 32)]; }
            Wl[k][l] = w;
        }
    }

    int srow[2], sq[2];
    #pragma unroll
    for (int h = 0; h < 2; h++) { int fi = t * 2 + h; srow[h] = fi >> 3; sq[h] = fi & 7; }
    bool vr[2];
    #pragma unroll
    for (int h = 0; h < 2; h++) vr[h] = (base + srow[h]) < N_USERS;

    float4 pvd[2]; float2 pva[2], pvb[2]; float4 pw[2];

    #pragma unroll
    for (int h = 0; h < 2; h++) {
        pvd[h] = make_float4(0.f, 0.f, 0.f, 0.f);
        pva[h] = make_float2(0.f, 0.f); pvb[h] = make_float2(0.f, 0.f);
        if (vr[h]) {
            const float* xp = xr + (size_t)(base + srow[h]) * 1544 + sq[h] * 4;
            pvd[h] = *(const float4*)(xp + 776);
            pva[h] = *(const float2*)(xp + 6);
            pvb[h] = *(const float2*)(xp + 8);
        }
        int fi = t + h * 256;
        int k = fi >> 4, c4 = (fi & 15) * 4;
        pw[h] = (c4 < 32) ? *(const float4*)(Wd + (size_t)k * 32 + c4)
                          : *(const float4*)(Wt + (size_t)k * 32 + (c4 - 32));
    }

    float acc[4][4];
    #pragma unroll
    for (int r = 0; r < 4; r++)
        #pragma unroll
        for (int c = 0; c < 4; c++) acc[r][c] = 0.f;

    for (int kc = 0; kc < 768; kc += 32) {
        __syncthreads();
        #pragma unroll
        for (int h = 0; h < 2; h++) {
            int k0 = sq[h] * 4, row = srow[h];
            XsD[k0 + 0][row] = pvd[h].x; XsD[k0 + 1][row] = pvd[h].y;
            XsD[k0 + 2][row] = pvd[h].z; XsD[k0 + 3][row] = pvd[h].w;
            XsT[k0 + 0][row] = pva[h].x; XsT[k0 + 1][row] = pva[h].y;
            XsT[k0 + 2][row] = pvb[h].x; XsT[k0 + 3][row] = pvb[h].y;
            int fi = t + h * 256;
            int k = fi >> 4, c4 = (fi & 15) * 4;
            *(float4*)&Ws[k][c4] = pw[h];
        }
        __syncthreads();
        int kn = kc + 32;
        if (kn < 768) {
            #pragma unroll
            for (int h = 0; h < 2; h++) {
                if (vr[h]) {
                    const float* xp = xr + (size_t)(base + srow[h]) * 1544 + kn + sq[h] * 4;
                    pvd[h] = *(const float4*)(xp + 776);
                    pva[h] = *(const float2*)(xp + 6);
                    pvb[h] = *(const float2*)(xp + 8);
                }
                int fi = t + h * 256;
                int k = fi >> 4, c4 = (fi & 15) * 4;
                pw[h] = (c4 < 32) ? *(const float4*)(Wd + (size_t)(kn + k) * 32 + c4)
                                  : *(const float4*)(Wt + (size_t)(kn + k) * 32 + (c4 - 32));
            }
        }

        const float* Xp = (cg < 8) ? &XsD[0][0] : &XsT[0][0];
        #pragma unroll 8
        for (int k = 0; k < 32; k++) {
            float4 xv = *(const float4*)(Xp + k * 68 + rg * 4);
            float4 wv = *(const float4*)&Ws[k][cg * 4];
            acc[0][0] = fmaf(xv.x, wv.x, acc[0][0]);
            acc[0][1] = fmaf(xv.x, wv.y, acc[0][1]);
            acc[0][2] = fmaf(xv.x, wv.z, acc[0][2]);
            acc[0][3] = fmaf(xv.x, wv.w, acc[0][3]);
            acc[1][0] = fmaf(xv.y, wv.x, acc[1][0]);
            acc[1][1] = fmaf(xv.y, wv.y, acc[1][1]);
            acc[1][2] = fmaf(xv.y, wv.z, acc[1][2]);
            acc[1][3] = fmaf(xv.y, wv.w, acc[1][3]);
            acc[2][0] = fmaf(xv.z, wv.x, acc[2][0]);
            acc[2][1] = fmaf(xv.z, wv.y, acc[2][1]);
            acc[2][2] = fmaf(xv.z, wv.z, acc[2][2]);
            acc[2][3] = fmaf(xv.z, wv.w, acc[2][3]);
            acc[3][0] = fmaf(xv.w, wv.x, acc[3][0]);
            acc[3][1] = fmaf(xv.w, wv.y, acc[3][1]);
            acc[3][2] = fmaf(xv.w, wv.z, acc[3][2]);
            acc[3][3] = fmaf(xv.w, wv.w, acc[3][3]);
        }
    }

    float bh[4], bl[4], wlv[8][4];
    #pragma unroll
    for (int c = 0; c < 4; c++) {
        int j = cg * 4 + c;
        bh[c] = (j < 32) ? bd[j] : bt[j - 32];
        bl[c] = (j < 32) ? bn[j] : bc[j - 32];
        #pragma unroll
        for (int k = 0; k < 8; k++) wlv[k][c] = Wl[k][j];
    }
    #pragma unroll
    for (int r = 0; r < 4; r++) {
        int lr = rg * 4 + r;
        int row = base + lr;
        if (row >= N_USERS) break;
        float4 hv;
        float* ph = &hv.x;
        #pragma unroll
        for (int c = 0; c < 4; c++) {
            float v = acc[r][c] + bh[c];
            ph[c] = v > 0.f ? v : 0.01f * v;
        }
        *(float4*)(h128 + (size_t)row * 128 + cg * 4) = hv;
        float4 lv;
        float* pl = &lv.x;
        #pragma unroll
        for (int c = 0; c < 4; c++) {
            float v = bl[c];
            #pragma unroll
            for (int k = 0; k < 8; k++) v = fmaf(xnc[lr][k], wlv[k][c], v);
            pl[c] = v > 0.f ? v : 0.01f * v;
        }
        *(float4*)(h128 + (size_t)row * 128 + 64 + cg * 4) = lv;
    }
}

// ---------------- fused dual GEMM: U = (prelu(X@W1+b1)) @ W2 -----------------
__global__ __launch_bounds__(256) void k_gemm2(
    const float* __restrict__ X, const float* __restrict__ W1,
    const float* __restrict__ b1, const float* __restrict__ pa,
    const float* __restrict__ W2, float* __restrict__ OUT, int n)
{
    __shared__ float Xs[32][132];
    __shared__ float Ws[32][132];
    int t = threadIdx.x;
    int cg = t & 31, rg = t >> 5;
    int base = blockIdx.x * 32;

    #pragma unroll
    for (int h = 0; h < 4; h++) {
        int fi = t + h * 256;
        int row = fi >> 5, q = fi & 31;
        float4 v = {0.f, 0.f, 0.f, 0.f};
        if (base + row < n) v = *(const float4*)(X + (size_t)(base + row) * 128 + q * 4);
        *(float4*)&Xs[row][q * 4] = v;
    }

    float acc[4][4];
    #pragma unroll
    for (int r = 0; r < 4; r++)
        #pragma unroll
        for (int c = 0; c < 4; c++) acc[r][c] = 0.f;

    for (int kc = 0; kc < 128; kc += 32) {
        __syncthreads();
        #pragma unroll
        for (int h = 0; h < 4; h++) {
            int fi = t + h * 256;
            int k = fi >> 5, q = fi & 31;
            *(float4*)&Ws[k][q * 4] = *(const float4*)(W1 + (size_t)(kc + k) * 128 + q * 4);
        }
        __syncthreads();
        #pragma unroll
        for (int k4 = 0; k4 < 8; k4++) {
            int k = k4 * 4;
            float4 w0 = *(const float4*)&Ws[k + 0][cg * 4];
            float4 w1 = *(const float4*)&Ws[k + 1][cg * 4];
            float4 w2 = *(const float4*)&Ws[k + 2][cg * 4];
            float4 w3 = *(const float4*)&Ws[k + 3][cg * 4];
            #pragma unroll
            for (int r = 0; r < 4; r++) {
                float4 xv = *(const float4*)&Xs[rg * 4 + r][kc + k];
                acc[r][0] = fmaf(xv.w, w3.x, fmaf(xv.z, w2.x, fmaf(xv.y, w1.x, fmaf(xv.x, w0.x, acc[r][0]))));
                acc[r][1] = fmaf(xv.w, w3.y, fmaf(xv.z, w2.y, fmaf(xv.y, w1.y, fmaf(xv.x, w0.y, acc[r][1]))));
                acc[r][2] = fmaf(xv.w, w3.z, fmaf(xv.z, w2.z, fmaf(xv.y, w1.z, fmaf(xv.x, w0.z, acc[r][2]))));
                acc[r][3] = fmaf(xv.w, w3.w, fmaf(xv.z, w2.w, fmaf(xv.y, w1.w, fmaf(xv.x, w0.w, acc[r][3]))));
            }
        }
    }

    float4 bv = *(const float4*)(b1 + cg * 4);
    float4 pv = *(const float4*)(pa + cg * 4);
    __syncthreads();
    #pragma unroll
    for (int r = 0; r < 4; r++) {
        float v0 = acc[r][0] + bv.x; v0 = v0 > 0.f ? v0 : pv.x * v0;
        float v1 = acc[r][1] + bv.y; v1 = v1 > 0.f ? v1 : pv.y * v1;
        float v2 = acc[r][2] + bv.z; v2 = v2 > 0.f ? v2 : pv.z * v2;
        float v3 = acc[r][3] + bv.w; v3 = v3 > 0.f ? v3 : pv.w * v3;
        Xs[rg * 4 + r][cg * 4 + 0] = v0;
        Xs[rg * 4 + r][cg * 4 + 1] = v1;
        Xs[rg * 4 + r][cg * 4 + 2] = v2;
        Xs[rg * 4 + r][cg * 4 + 3] = v3;
        acc[r][0] = 0.f; acc[r][1] = 0.f; acc[r][2] = 0.f; acc[r][3] = 0.f;
    }

    for (int kc = 0; kc < 128; kc += 32) {
        __syncthreads();
        #pragma unroll
        for (int h = 0; h < 4; h++) {
            int fi = t + h * 256;
            int k = fi >> 5, q = fi & 31;
            *(float4*)&Ws[k][q * 4] = *(const float4*)(W2 + (size_t)(kc + k) * 128 + q * 4);
        }
        __syncthreads();
        #pragma unroll
        for (int k4 = 0; k4 < 8; k4++) {
            int k = k4 * 4;
            float4 w0 = *(const float4*)&Ws[k + 0][cg * 4];
            float4 w1 = *(const float4*)&Ws[k + 1][cg * 4];
            float4 w2 = *(const float4*)&Ws[k + 2][cg * 4];
            float4 w3 = *(const float4*)&Ws[k + 3][cg * 4];
            #pragma unroll
            for (int r = 0; r < 4; r++) {
                float4 xv = *(const float4*)&Xs[rg * 4 + r][kc + k];
                acc[r][0] = fmaf(xv.w, w3.x, fmaf(xv.z, w2.x, fmaf(xv.y, w1.x, fmaf(xv.x, w0.x, acc[r][0]))));
                acc[r][1] = fmaf(xv.w, w3.y, fmaf(xv.z, w2.y, fmaf(xv.y, w1.y, fmaf(xv.x, w0.y, acc[r][1]))));
                acc[r][2] = fmaf(xv.w, w3.z, fmaf(xv.z, w2.z, fmaf(xv.y, w1.z, fmaf(xv.x, w0.z, acc[r][2]))));
                acc[r][3] = fmaf(xv.w, w3.w, fmaf(xv.z, w2.w, fmaf(xv.y, w1.w, fmaf(xv.x, w0.w, acc[r][3]))));
            }
        }
    }

    #pragma unroll
    for (int r = 0; r < 4; r++) {
        int row = base + rg * 4 + r;
        if (row >= n) break;
        float4 v;
        v.x = acc[r][0]; v.y = acc[r][1]; v.z = acc[r][2]; v.w = acc[r][3];
        *(float4*)(OUT + (size_t)row * 128 + cg * 4) = v;
    }
}

// ---------------- [n,128] @ [128,128] GEMM, 4x4 register tile ----------------
__global__ __launch_bounds__(256) void k_gemmT(
    const float* X, const float* __restrict__ W, float* OUT, int n)
{
    __shared__ float Xs[32][132];
    __shared__ float Ws[32][132];
    int t = threadIdx.x;
    int cg = t & 31, rg = t >> 5;
    int base = blockIdx.x * 32;

    #pragma unroll
    for (int h = 0; h < 4; h++) {
        int fi = t + h * 256;
        int row = fi >> 5, q = fi & 31;
        float4 v = {0.f, 0.f, 0.f, 0.f};
        if (base + row < n) v = *(const float4*)(X + (size_t)(base + row) * 128 + q * 4);
        *(float4*)&Xs[row][q * 4] = v;
    }

    float acc[4][4];
    #pragma unroll
    for (int r = 0; r < 4; r++)
        #pragma unroll
        for (int c = 0; c < 4; c++) acc[r][c] = 0.f;

    for (int kc = 0; kc < 128; kc += 32) {
        __syncthreads();
        #pragma unroll
        for (int h = 0; h < 4; h++) {
            int fi = t + h * 256;
            int k = fi >> 5, q = fi & 31;
            *(float4*)&Ws[k][q * 4] = *(const float4*)(W + (size_t)(kc + k) * 128 + q * 4);
        }
        __syncthreads();
        #pragma unroll
        for (int k4 = 0; k4 < 8; k4++) {
            int k = k4 * 4;
            float4 w0 = *(const float4*)&Ws[k + 0][cg * 4];
            float4 w1 = *(const float4*)&Ws[k + 1][cg * 4];
            float4 w2 = *(const float4*)&Ws[k + 2][cg * 4];
            float4 w3 = *(const float4*)&Ws[k + 3][cg * 4];
            #pragma unroll
            for (int r = 0; r < 4; r++) {
                float4 xv = *(const float4*)&Xs[rg * 4 + r][kc + k];
                acc[r][0] = fmaf(xv.w, w3.x, fmaf(xv.z, w2.x, fmaf(xv.y, w1.x, fmaf(xv.x, w0.x, acc[r][0]))));
                acc[r][1] = fmaf(xv.w, w3.y, fmaf(xv.z, w2.y, fmaf(xv.y, w1.y, fmaf(xv.x, w0.y, acc[r][1]))));
                acc[r][2] = fmaf(xv.w, w3.z, fmaf(xv.z, w2.z, fmaf(xv.y, w1.z, fmaf(xv.x, w0.z, acc[r][2]))));
                acc[r][3] = fmaf(xv.w, w3.w, fmaf(xv.z, w2.w, fmaf(xv.y, w1.w, fmaf(xv.x, w0.w, acc[r][3]))));
            }
        }
    }

    #pragma unroll
    for (int r = 0; r < 4; r++) {
        int row = base + rg * 4 + r;
        if (row >= n) break;
        float4 v;
        v.x = acc[r][0]; v.y = acc[r][1]; v.z = acc[r][2]; v.w = acc[r][3];
        *(float4*)(OUT + (size_t)row * 128 + cg * 4) = v;
    }
}

// ---------------- fused CSR build over 5 segments ----------------------------
__device__ __forceinline__ void seg_of_scanblk(int b, int& doff, int& bsoff, int& lb) {
    if (b < 196)      { doff = 0;      bsoff = 0;   lb = b; }
    else if (b < 245) { doff = 200704; bsoff = 196; lb = b - 196; }
    else if (b < 258) { doff = 250880; bsoff = 245; lb = b - 245; }
    else if (b < 307) { doff = 264192; bsoff = 258; lb = b - 258; }
    else              { doff = 314368; bsoff = 307; lb = b - 307; }
}

__global__ __launch_bounds__(256) void k_count_all(
    const int* __restrict__ d0, const int* __restrict__ d1, const int* __restrict__ d2,
    const int* __restrict__ p1, const int* __restrict__ p2,
    int* __restrict__ degs, int* __restrict__ ranks)
{
    int t0 = blockIdx.x * 256 + threadIdx.x;
    if (t0 >= 587500) return;
    #pragma unroll
    for (int k = 0; k < 4; k++) {
        int gid = t0 + k * 587500;
        int idx;
        if (gid < 1600000)      idx = d0[gid];
        else if (gid < 2000000) idx = 200704 + d1[gid - 1600000];
        else if (gid < 2100000) idx = 250880 + d2[gid - 2000000];
        else if (gid < 2300000) idx = 264192 + p1[gid - 2100000];
        else                    idx = 314368 + p2[gid - 2300000];
        ranks[gid] = atomicAdd(&degs[idx], 1);
    }
}

__global__ __launch_bounds__(256) void k_scan_all(
    const int* __restrict__ degs, int* __restrict__ rowsts, int* __restrict__ bsums)
{
    __shared__ int sh[256];
    int doff, bsoff, lb;
    seg_of_scanblk(blockIdx.x, doff, bsoff, lb);
    int t = threadIdx.x;
    int base = doff + lb * 1024 + t * 4;
    int v[4], s = 0;
    #pragma unroll
    for (int k = 0; k < 4; k++) { v[k] = degs[base + k]; s += v[k]; }
    sh[t] = s;
    __syncthreads();
    for (int off = 1; off < 256; off <<= 1) {
        int x = 0;
        if (t >= off) x = sh[t - off];
        __syncthreads();
        if (t >= off) sh[t] += x;
        __syncthreads();
    }
    int ex = sh[t] - s;
    if (t == 255) bsums[bsoff + lb] = sh[255];
    #pragma unroll
    for (int k = 0; k < 4; k++) { rowsts[base + k] = ex; ex += v[k]; }
}

// add block offsets (self-computed prefix of raw bsums) + dinv for segs 0-2
__global__ __launch_bounds__(256) void k_scanadd_all(
    int* __restrict__ rowsts, const int* __restrict__ bsums,
    const int* __restrict__ degs, float* __restrict__ dinvs)
{
    __shared__ int sh[256];
    int doff, bsoff, lb;
    seg_of_scanblk(blockIdx.x, doff, bsoff, lb);
    int t = threadIdx.x;
    sh[t] = (t < lb) ? bsums[bsoff + t] : 0;
    __syncthreads();
    #pragma unroll
    for (int off = 128; off >= 1; off >>= 1) {
        if (t < off) sh[t] += sh[t + off];
        __syncthreads();
    }
    int add = sh[0];
    int base = doff + lb * 1024 + t * 4;
    bool dodinv = (doff <= 250880);
    #pragma unroll
    for (int k = 0; k < 4; k++) {
        int i = base + k;
        rowsts[i] += add;
        if (dodinv) dinvs[i] = rsqrtf((float)degs[i] + 1.0f);
    }
}

// atomic-free scatter; edge segs also store per-edge src weight (dinv[src]),
// and seg0 resolves nodelist: elist[p] = nl[src]  (chain-shortening for gather)
__global__ __launch_bounds__(256) void k_scatter_all(
    const int* __restrict__ s0, const int* __restrict__ d0,
    const int* __restrict__ s1, const int* __restrict__ d1,
    const int* __restrict__ s2, const int* __restrict__ d2,
    const int* __restrict__ p1, const int* __restrict__ p2,
    const int* __restrict__ nl, const float* __restrict__ dinvs,
    const int* __restrict__ rowsts, const int* __restrict__ ranks,
    int* __restrict__ elists, float* __restrict__ edw)
{
    int t0 = blockIdx.x * 256 + threadIdx.x;
    if (t0 >= 587500) return;
    #pragma unroll
    for (int k = 0; k < 4; k++) {
        int gid = t0 + k * 587500;
        if (gid < 1600000) {
            int s = s0[gid];
            int p = rowsts[d0[gid]] + ranks[gid];
            elists[p] = nl[s];
            edw[p] = dinvs[s];
        } else if (gid < 2000000) {
            int i = gid - 1600000;
            int s = s1[i];
            int p = rowsts[200704 + d1[i]] + ranks[gid];
            elists[1600000 + p] = s;
            edw[1600000 + p] = dinvs[200704 + s];
        } else if (gid < 2100000) {
            int i = gid - 2000000;
            int s = s2[i];
            int p = rowsts[250880 + d2[i]] + ranks[gid];
            elists[2000000 + p] = s;
            edw[2000000 + p] = dinvs[250880 + s];
        } else if (gid < 2300000) {
            int i = gid - 2100000;
            int p = rowsts[264192 + p1[i]] + ranks[gid];
            elists[2100000 + p] = i;
        } else {
            int i = gid - 2300000;
            int p = rowsts[314368 + p2[i]] + ranks[gid];
            elists[2300000 + p] = i;
        }
    }
}

// ---------------- GCN pieces -------------------------------------------------
// L0: out[d] = relu((U[nl[d]]*dd + sum_e U[elist[e]]*edw[e]) * dd + b)
__global__ __launch_bounds__(256) void k_gatherU(
    const float* __restrict__ U, const int* __restrict__ nl,
    const int* __restrict__ rowst, const int* __restrict__ elist,
    const float* __restrict__ edw, const float* __restrict__ dinv,
    const float* __restrict__ bias, float* __restrict__ out, int n)
{
    size_t gid = (size_t)blockIdx.x * 256 + threadIdx.x;
    int d = (int)(gid >> 5);
    if (d >= n) return;
    int l = (int)(gid & 31);
    const float4* Uv = (const float4*)U;
    float dd = dinv[d];
    float4 self = Uv[(size_t)nl[d] * 32 + l];
    float4 acc;
    acc.x = self.x * dd; acc.y = self.y * dd; acc.z = self.z * dd; acc.w = self.w * dd;
    int s0 = rowst[d], s1 = rowst[d + 1];
    for (int e = s0; e < s1; ++e) {
        int srow = elist[e];
        float w = edw[e];
        float4 v = Uv[(size_t)srow * 32 + l];
        acc.x = fmaf(v.x, w, acc.x);
        acc.y = fmaf(v.y, w, acc.y);
        acc.z = fmaf(v.z, w, acc.z);
        acc.w = fmaf(v.w, w, acc.w);
    }
    const float4 b = ((const float4*)bias)[l];
    float4 y;
    y.x = fmaxf(fmaf(acc.x, dd, b.x), 0.f);
    y.y = fmaxf(fmaf(acc.y, dd, b.y), 0.f);
    y.z = fmaxf(fmaf(acc.z, dd, b.z), 0.f);
    y.w = fmaxf(fmaf(acc.w, dd, b.w), 0.f);
    ((float4*)out)[(size_t)d * 32 + l] = y;
}

// L1/L2: out[d] = relu((h[d]*dd + sum_e h[elist[e]]*edw[e]) * dd + b)
__global__ __launch_bounds__(256) void k_gather(
    const float* __restrict__ h, const int* __restrict__ rowst,
    const int* __restrict__ elist, const float* __restrict__ edw,
    const float* __restrict__ dinv, const float* __restrict__ bias,
    float* __restrict__ out, int n)
{
    size_t gid = (size_t)blockIdx.x * 256 + threadIdx.x;
    int d = (int)(gid >> 5);
    if (d >= n) return;
    int l = (int)(gid & 31);
    const float4* hv = (const float4*)h;
    float dd = dinv[d];
    float4 self = hv[(size_t)d * 32 + l];
    float4 acc;
    acc.x = self.x * dd; acc.y = self.y * dd; acc.z = self.z * dd; acc.w = self.w * dd;
    int s0 = rowst[d], s1 = rowst[d + 1];
    for (int e = s0; e < s1; ++e) {
        int srow = elist[e];
        float w = edw[e];
        float4 v = hv[(size_t)srow * 32 + l];
        acc.x = fmaf(v.x, w, acc.x);
        acc.y = fmaf(v.y, w, acc.y);
        acc.z = fmaf(v.z, w, acc.z);
        acc.w = fmaf(v.w, w, acc.w);
    }
    const float4 b = ((const float4*)bias)[l];
    float4 y;
    y.x = fmaxf(fmaf(acc.x, dd, b.x), 0.f);
    y.y = fmaxf(fmaf(acc.y, dd, b.y), 0.f);
    y.z = fmaxf(fmaf(acc.z, dd, b.z), 0.f);
    y.w = fmaxf(fmaf(acc.w, dd, b.w), 0.f);
    ((float4*)out)[(size_t)d * 32 + l] = y;
}

__global__ __launch_bounds__(256) void k_poolgather(
    const float* __restrict__ Y, const int* __restrict__ rowst,
    const int* __restrict__ elist, float* __restrict__ out, int np)
{
    size_t gid = (size_t)blockIdx.x * 256 + threadIdx.x;
    int p = (int)(gid >> 5);
    if (p >= np) return;
    int l = (int)(gid & 31);
    const float4* yv = (const float4*)Y;
    float4 acc = {0.f, 0.f, 0.f, 0.f};
    int s0 = rowst[p], s1 = rowst[p + 1];
    for (int e = s0; e < s1; ++e) {
        int i = elist[e];
        float4 v = yv[(size_t)i * 32 + l];
        acc.x += v.x; acc.y += v.y; acc.z += v.z; acc.w += v.w;
    }
    float4 y;
    y.x = fmaxf(acc.x, 0.f); y.y = fmaxf(acc.y, 0.f);
    y.z = fmaxf(acc.z, 0.f); y.w = fmaxf(acc.w, 0.f);
    ((float4*)out)[(size_t)p * 32 + l] = y;
}

__global__ __launch_bounds__(128) void k_bpool_all(
    const float* __restrict__ X1, const float* __restrict__ X2, const float* __restrict__ Y2,
    const int* __restrict__ b1, const int* __restrict__ b2, float* __restrict__ pl)
{
    int b = blockIdx.x;
    const float* src; const int* bidx; int coloff, n, r0;
    if (b < 391)      { src = X1; bidx = b1; coloff = 0;   n = 50000; r0 = b * 128; }
    else if (b < 489) { src = X2; bidx = b2; coloff = 128; n = 12500; r0 = (b - 391) * 128; }
    else              { src = Y2; bidx = b2; coloff = 256; n = 12500; r0 = (b - 489) * 128; }
    if (r0 >= n) return;
    int j = threadIdx.x;
    int r1 = min(r0 + 128, n);
    float acc = 0.f;
    int prev = bidx[r0];
    for (int r = r0; r < r1; ++r) {
        int bb = bidx[r];
        if (bb != prev) {
            unsafeAtomicAdd(&pl[(size_t)prev * 384 + coloff + j], acc);
            acc = 0.f; prev = bb;
        }
        acc += src[(size_t)r * 128 + j];
    }
    unsafeAtomicAdd(&pl[(size_t)prev * 384 + coloff + j], acc);
}

// fused 2-layer MLP
__global__ void k_mlp2(const float* __restrict__ PL,
                       const float* __restrict__ Wc1, const float* __restrict__ bc1,
                       const float* __restrict__ Wc2, const float* __restrict__ bc2,
                       float* __restrict__ out)
{
    __shared__ float as[384];
    __shared__ float zs[128];
    int r = blockIdx.x, j = threadIdx.x;
    as[j] = PL[(size_t)r * 384 + j];
    as[j + 128] = PL[(size_t)r * 384 + 128 + j];
    as[j + 256] = PL[(size_t)r * 384 + 256 + j];
    __syncthreads();
    float acc = bc1[j];
    for (int k = 0; k < 384; k++) acc = fmaf(as[k], Wc1[(size_t)k * 128 + j], acc);
    zs[j] = fmaxf(acc, 0.f);
    __syncthreads();
    float o = bc2[j];
    for (int k = 0; k < 128; k++) o = fmaf(zs[k], Wc2[(size_t)k * 128 + j], o);
    out[(size_t)r * 128 + j] = o;
}

extern "C" void kernel_launch(void* const* d_in, const int* in_sizes, int n_in,
                              void* d_out, int out_size, void* d_ws, size_t ws_size,
                              hipStream_t stream)
{
    const float* x_raw  = (const float*)d_in[0];
    const float* W_des  = (const float*)d_in[1];
    const float* b_des  = (const float*)d_in[2];
    const float* W_twe  = (const float*)d_in[3];
    const float* b_twe  = (const float*)d_in[4];
    const float* W_num  = (const float*)d_in[5];
    const float* b_num  = (const float*)d_in[6];
    const float* W_cat  = (const float*)d_in[7];
    const float* b_cat  = (const float*)d_in[8];
    const float* W_in   = (const float*)d_in[9];
    const float* b_in   = (const float*)d_in[10];
    const float* prelua = (const float*)d_in[11];
    const float* W_conv = (const float*)d_in[12];
    const float* b_conv = (const float*)d_in[13];
    const float* Wc1    = (const float*)d_in[14];
    const float* bc1    = (const float*)d_in[15];
    const float* Wc2    = (const float*)d_in[16];
    const float* bc2    = (const float*)d_in[17];
    const int* nodelist = (const int*)d_in[18];
    const int* e0       = (const int*)d_in[19];
    const int* e1       = (const int*)d_in[20];
    const int* e2       = (const int*)d_in[21];
    const int* parent1  = (const int*)d_in[22];
    const int* parent2  = (const int*)d_in[23];
    const int* batch1   = (const int*)d_in[24];
    const int* batch2   = (const int*)d_in[25];

    // ---- workspace layout ----
    float* WS  = (float*)d_ws;
    float* ENC = WS;                    // 50000*128; dead after k_gemm2
    // CSR scratch aliases ENC (built after k_gemm2): 22.5 MB < 25.6 MB
    int*   DEGS   = (int*)d_ws;                 // 327680
    int*   ROWSTS = DEGS + 327680;              // 327680
    float* DINVS  = (float*)(ROWSTS + 327680);  // 264192
    int*   BSUMS  = (int*)(DINVS + 264192);     // 512
    int*   RANKS  = BSUMS + 512;                // 2350000
    int*   ELISTS = RANKS + 2350000;            // 2350000
    float* U  = WS + 6400000;           // 50000*128
    float* H  = WS + 12800000;          // 50000*128
    float* Y  = WS + 19200000;          // 200000*128 (L0 gcn out; reused L1/L2)
    float* X1 = WS + 44800000;          // 50000*128
    float* X2 = WS + 51200000;          // 12500*128
    float* PL = WS + 52800000;          // 128*384
    float* EDW = WS + 52900000;         // 2100000 per-edge src weights

    hipMemsetAsync(PL, 0, (size_t)128 * 384 * 4, stream);

    // ---- encoder -> ENC; U = prelu(ENC@W_in+b)@W_conv0 (fused) ----
    k_enc3<<<(N_USERS + 63) / 64, 256, 0, stream>>>(
        x_raw, W_des, b_des, W_twe, b_twe, W_num, b_num, W_cat, b_cat, ENC);
    k_gemm2<<<(N_USERS + 31) / 32, 256, 0, stream>>>(
        ENC, W_in, b_in, prelua, W_conv, U, N_USERS);

    // ---- fused CSR builds (+dinv, +edge weights); clobbers ENC (dead) ----
    hipMemsetAsync(DEGS, 0, (size_t)327680 * 4, stream);
    k_count_all<<<(587500 + 255) / 256, 256, 0, stream>>>(
        e0 + EE0, e1 + EE1, e2 + EE2, parent1, parent2, DEGS, RANKS);
    k_scan_all<<<320, 256, 0, stream>>>(DEGS, ROWSTS, BSUMS);
    k_scanadd_all<<<320, 256, 0, stream>>>(ROWSTS, BSUMS, DEGS, DINVS);
    k_scatter_all<<<(587500 + 255) / 256, 256, 0, stream>>>(
        e0, e0 + EE0, e1, e1 + EE1, e2, e2 + EE2, parent1, parent2,
        nodelist, DINVS, ROWSTS, RANKS, ELISTS, EDW);

    // ---- layer 0: GCN over NN0 -> Y; pool -> X1 ----
    k_gatherU<<<(int)(((size_t)NN0 * 32 + 255) / 256), 256, 0, stream>>>(
        U, nodelist, ROWSTS, ELISTS, EDW, DINVS, b_conv, Y, NN0);
    k_poolgather<<<(int)(((size_t)NN1 * 32 + 255) / 256), 256, 0, stream>>>(
        Y, ROWSTS + 264192, ELISTS + 2100000, X1, NN1);

    // ---- layer 1 ----
    k_gemmT<<<(NN1 + 31) / 32, 256, 0, stream>>>(X1, W_conv + 16384, H, NN1);
    k_gather<<<(int)(((size_t)NN1 * 32 + 255) / 256), 256, 0, stream>>>(
        H, ROWSTS + 200704, ELISTS + 1600000, EDW + 1600000, DINVS + 200704,
        b_conv + 128, Y, NN1);
    k_poolgather<<<(int)(((size_t)NN2 * 32 + 255) / 256), 256, 0, stream>>>(
        Y, ROWSTS + 314368, ELISTS + 2300000, X2, NN2);

    // ---- layer 2 ----
    k_gemmT<<<(NN2 + 31) / 32, 256, 0, stream>>>(X2, W_conv + 32768, H, NN2);
    k_gather<<<(int)(((size_t)NN2 * 32 + 255) / 256), 256, 0, stream>>>(
        H, ROWSTS + 250880, ELISTS + 2000000, EDW + 2000000, DINVS + 250880,
        b_conv + 256, Y, NN2);

    // ---- batch pooling (fused, sorted keys) ----
    k_bpool_all<<<587, 128, 0, stream>>>(X1, X2, Y, batch1, batch2, PL);

    // ---- final fused MLP ----
    k_mlp2<<<128, 128, 0, stream>>>(PL, Wc1, bc1, Wc2, bc2, (float*)d_out);
}

// Round 10
// 755.582 us; speedup vs baseline: 1.1232x; 1.0489x over previous
//
#include <hip/hip_runtime.h>

#define N_USERS 50000
#define NN0 200000
#define NN1 50000
#define NN2 12500
#define EE0 1600000
#define EE1 400000
#define EE2 100000

// Padded segment geometry for fused CSR builds (padded to 1024 multiples):
// seg:      0:e0        1:e1      2:e2      3:parent1  4:parent2
// deg off:  0           200704    250880    264192     314368   (total 327680)
// scan blk: 196         49        13        49         13       (cum 196,245,258,307,320)
// bsum off: 0           196       245       258        307
// el off:   0           1600000   2000000   2100000    2300000

// ---------------- encoder: h128[r] = leaky([d|t|n|c]) -------------------------
// 64 rows x 64 heavy cols per block; thread = 4 rows x 4 cols.
// Staging mapping row-fast across lanes -> conflict-free LDS writes (2/bank).
__global__ __launch_bounds__(256) void k_enc3(
    const float* __restrict__ xr,
    const float* __restrict__ Wd, const float* __restrict__ bd,
    const float* __restrict__ Wt, const float* __restrict__ bt,
    const float* __restrict__ Wn, const float* __restrict__ bn,
    const float* __restrict__ Wc, const float* __restrict__ bc,
    float* __restrict__ h128)
{
    __shared__ float XsD[32][68];  // [k][row] des chunk (transposed)
    __shared__ float XsT[32][68];  // [k][row] tweet chunk
    __shared__ float Ws[32][68];   // [k][col 0..63] = [Wd|Wt]
    __shared__ float xnc[64][8];
    __shared__ float Wl[8][64];

    int t = threadIdx.x;
    int cg = t & 15, rg = t >> 4;
    int base = blockIdx.x * 64;

    if (t < 64) {
        int row = base + t;
        if (row < N_USERS) {
            const float* xp = xr + (size_t)row * 1544;
            float4 a = *(const float4*)xp;
            float2 b2 = *(const float2*)(xp + 4);
            float2 c2 = *(const float2*)(xp + 774);
            xnc[t][0] = a.x; xnc[t][1] = a.y; xnc[t][2] = a.z; xnc[t][3] = a.w;
            xnc[t][4] = b2.x; xnc[t][5] = b2.y; xnc[t][6] = c2.x; xnc[t][7] = c2.y;
        } else {
            #pragma unroll
            for (int k = 0; k < 8; k++) xnc[t][k] = 0.f;
        }
    } else if (t >= 192) {
        int l = t - 192;
        #pragma unroll
        for (int k = 0; k < 8; k++) {
            float w = 0.f;
            if (l < 32) { if (k < 6) w = Wn[k * 32 + l]; }
            else        { if (k >= 6) w = Wc[(k - 6) * 32 + (l - 32)]; }
            Wl[k][l] = w;
        }
    }

    float acc[4][4];
    #pragma unroll
    for (int r = 0; r < 4; r++)
        #pragma unroll
        for (int c = 0; c < 4; c++) acc[r][c] = 0.f;

    for (int kc = 0; kc < 768; kc += 32) {
        __syncthreads();
        // stage X: row-fast lane mapping; per-instruction lanes hit 64
        // consecutive [k][row] slots -> 2 lanes/bank (free)
        #pragma unroll
        for (int h = 0; h < 2; h++) {
            int fi = t + h * 256;
            int row = fi & 63, q = fi >> 6;   // q in 0..7 across h
            int grow = base + row;
            float4 vd = {0.f, 0.f, 0.f, 0.f};
            float2 va = {0.f, 0.f}, vb = {0.f, 0.f};
            if (grow < N_USERS) {
                const float* xp = xr + (size_t)grow * 1544 + kc + q * 4;
                vd = *(const float4*)(xp + 776);  // 16B aligned
                va = *(const float2*)(xp + 6);    // 8B aligned
                vb = *(const float2*)(xp + 8);
            }
            int k0 = q * 4;
            XsD[k0 + 0][row] = vd.x; XsD[k0 + 1][row] = vd.y;
            XsD[k0 + 2][row] = vd.z; XsD[k0 + 3][row] = vd.w;
            XsT[k0 + 0][row] = va.x; XsT[k0 + 1][row] = va.y;
            XsT[k0 + 2][row] = vb.x; XsT[k0 + 3][row] = vb.y;
        }
        // stage W chunk [32k][64c] (512 float4 = 2 x 256)
        #pragma unroll
        for (int h = 0; h < 2; h++) {
            int fi = t + h * 256;
            int k = fi >> 4, c4 = (fi & 15) * 4;
            float4 w = (c4 < 32) ? *(const float4*)(Wd + (size_t)(kc + k) * 32 + c4)
                                 : *(const float4*)(Wt + (size_t)(kc + k) * 32 + (c4 - 32));
            *(float4*)&Ws[k][c4] = w;
        }
        __syncthreads();

        const float* Xp = (cg < 8) ? &XsD[0][0] : &XsT[0][0];
        #pragma unroll 8
        for (int k = 0; k < 32; k++) {
            float4 xv = *(const float4*)(Xp + k * 68 + rg * 4);
            float4 wv = *(const float4*)&Ws[k][cg * 4];
            acc[0][0] = fmaf(xv.x, wv.x, acc[0][0]);
            acc[0][1] = fmaf(xv.x, wv.y, acc[0][1]);
            acc[0][2] = fmaf(xv.x, wv.z, acc[0][2]);
            acc[0][3] = fmaf(xv.x, wv.w, acc[0][3]);
            acc[1][0] = fmaf(xv.y, wv.x, acc[1][0]);
            acc[1][1] = fmaf(xv.y, wv.y, acc[1][1]);
            acc[1][2] = fmaf(xv.y, wv.z, acc[1][2]);
            acc[1][3] = fmaf(xv.y, wv.w, acc[1][3]);
            acc[2][0] = fmaf(xv.z, wv.x, acc[2][0]);
            acc[2][1] = fmaf(xv.z, wv.y, acc[2][1]);
            acc[2][2] = fmaf(xv.z, wv.z, acc[2][2]);
            acc[2][3] = fmaf(xv.z, wv.w, acc[2][3]);
            acc[3][0] = fmaf(xv.w, wv.x, acc[3][0]);
            acc[3][1] = fmaf(xv.w, wv.y, acc[3][1]);
            acc[3][2] = fmaf(xv.w, wv.z, acc[3][2]);
            acc[3][3] = fmaf(xv.w, wv.w, acc[3][3]);
        }
    }

    float bh[4], bl[4], wlv[8][4];
    #pragma unroll
    for (int c = 0; c < 4; c++) {
        int j = cg * 4 + c;
        bh[c] = (j < 32) ? bd[j] : bt[j - 32];
        bl[c] = (j < 32) ? bn[j] : bc[j - 32];
        #pragma unroll
        for (int k = 0; k < 8; k++) wlv[k][c] = Wl[k][j];
    }
    #pragma unroll
    for (int r = 0; r < 4; r++) {
        int lr = rg * 4 + r;
        int row = base + lr;
        if (row >= N_USERS) break;
        float4 hv;
        float* ph = &hv.x;
        #pragma unroll
        for (int c = 0; c < 4; c++) {
            float v = acc[r][c] + bh[c];
            ph[c] = v > 0.f ? v : 0.01f * v;
        }
        *(float4*)(h128 + (size_t)row * 128 + cg * 4) = hv;
        float4 lv;
        float* pl = &lv.x;
        #pragma unroll
        for (int c = 0; c < 4; c++) {
            float v = bl[c];
            #pragma unroll
            for (int k = 0; k < 8; k++) v = fmaf(xnc[lr][k], wlv[k][c], v);
            pl[c] = v > 0.f ? v : 0.01f * v;
        }
        *(float4*)(h128 + (size_t)row * 128 + 64 + cg * 4) = lv;
    }
}

// ---------------- fused dual GEMM: U = (prelu(X@W1+b1)) @ W2 -----------------
__global__ __launch_bounds__(256) void k_gemm2(
    const float* __restrict__ X, const float* __restrict__ W1,
    const float* __restrict__ b1, const float* __restrict__ pa,
    const float* __restrict__ W2, float* __restrict__ OUT, int n)
{
    __shared__ float Xs[32][132];
    __shared__ float Ws[32][132];
    int t = threadIdx.x;
    int cg = t & 31, rg = t >> 5;
    int base = blockIdx.x * 32;

    #pragma unroll
    for (int h = 0; h < 4; h++) {
        int fi = t + h * 256;
        int row = fi >> 5, q = fi & 31;
        float4 v = {0.f, 0.f, 0.f, 0.f};
        if (base + row < n) v = *(const float4*)(X + (size_t)(base + row) * 128 + q * 4);
        *(float4*)&Xs[row][q * 4] = v;
    }

    float acc[4][4];
    #pragma unroll
    for (int r = 0; r < 4; r++)
        #pragma unroll
        for (int c = 0; c < 4; c++) acc[r][c] = 0.f;

    for (int kc = 0; kc < 128; kc += 32) {
        __syncthreads();
        #pragma unroll
        for (int h = 0; h < 4; h++) {
            int fi = t + h * 256;
            int k = fi >> 5, q = fi & 31;
            *(float4*)&Ws[k][q * 4] = *(const float4*)(W1 + (size_t)(kc + k) * 128 + q * 4);
        }
        __syncthreads();
        #pragma unroll
        for (int k4 = 0; k4 < 8; k4++) {
            int k = k4 * 4;
            float4 w0 = *(const float4*)&Ws[k + 0][cg * 4];
            float4 w1 = *(const float4*)&Ws[k + 1][cg * 4];
            float4 w2 = *(const float4*)&Ws[k + 2][cg * 4];
            float4 w3 = *(const float4*)&Ws[k + 3][cg * 4];
            #pragma unroll
            for (int r = 0; r < 4; r++) {
                float4 xv = *(const float4*)&Xs[rg * 4 + r][kc + k];
                acc[r][0] = fmaf(xv.w, w3.x, fmaf(xv.z, w2.x, fmaf(xv.y, w1.x, fmaf(xv.x, w0.x, acc[r][0]))));
                acc[r][1] = fmaf(xv.w, w3.y, fmaf(xv.z, w2.y, fmaf(xv.y, w1.y, fmaf(xv.x, w0.y, acc[r][1]))));
                acc[r][2] = fmaf(xv.w, w3.z, fmaf(xv.z, w2.z, fmaf(xv.y, w1.z, fmaf(xv.x, w0.z, acc[r][2]))));
                acc[r][3] = fmaf(xv.w, w3.w, fmaf(xv.z, w2.w, fmaf(xv.y, w1.w, fmaf(xv.x, w0.w, acc[r][3]))));
            }
        }
    }

    float4 bv = *(const float4*)(b1 + cg * 4);
    float4 pv = *(const float4*)(pa + cg * 4);
    __syncthreads();
    #pragma unroll
    for (int r = 0; r < 4; r++) {
        float v0 = acc[r][0] + bv.x; v0 = v0 > 0.f ? v0 : pv.x * v0;
        float v1 = acc[r][1] + bv.y; v1 = v1 > 0.f ? v1 : pv.y * v1;
        float v2 = acc[r][2] + bv.z; v2 = v2 > 0.f ? v2 : pv.z * v2;
        float v3 = acc[r][3] + bv.w; v3 = v3 > 0.f ? v3 : pv.w * v3;
        Xs[rg * 4 + r][cg * 4 + 0] = v0;
        Xs[rg * 4 + r][cg * 4 + 1] = v1;
        Xs[rg * 4 + r][cg * 4 + 2] = v2;
        Xs[rg * 4 + r][cg * 4 + 3] = v3;
        acc[r][0] = 0.f; acc[r][1] = 0.f; acc[r][2] = 0.f; acc[r][3] = 0.f;
    }

    for (int kc = 0; kc < 128; kc += 32) {
        __syncthreads();
        #pragma unroll
        for (int h = 0; h < 4; h++) {
            int fi = t + h * 256;
            int k = fi >> 5, q = fi & 31;
            *(float4*)&Ws[k][q * 4] = *(const float4*)(W2 + (size_t)(kc + k) * 128 + q * 4);
        }
        __syncthreads();
        #pragma unroll
        for (int k4 = 0; k4 < 8; k4++) {
            int k = k4 * 4;
            float4 w0 = *(const float4*)&Ws[k + 0][cg * 4];
            float4 w1 = *(const float4*)&Ws[k + 1][cg * 4];
            float4 w2 = *(const float4*)&Ws[k + 2][cg * 4];
            float4 w3 = *(const float4*)&Ws[k + 3][cg * 4];
            #pragma unroll
            for (int r = 0; r < 4; r++) {
                float4 xv = *(const float4*)&Xs[rg * 4 + r][kc + k];
                acc[r][0] = fmaf(xv.w, w3.x, fmaf(xv.z, w2.x, fmaf(xv.y, w1.x, fmaf(xv.x, w0.x, acc[r][0]))));
                acc[r][1] = fmaf(xv.w, w3.y, fmaf(xv.z, w2.y, fmaf(xv.y, w1.y, fmaf(xv.x, w0.y, acc[r][1]))));
                acc[r][2] = fmaf(xv.w, w3.z, fmaf(xv.z, w2.z, fmaf(xv.y, w1.z, fmaf(xv.x, w0.z, acc[r][2]))));
                acc[r][3] = fmaf(xv.w, w3.w, fmaf(xv.z, w2.w, fmaf(xv.y, w1.w, fmaf(xv.x, w0.w, acc[r][3]))));
            }
        }
    }

    #pragma unroll
    for (int r = 0; r < 4; r++) {
        int row = base + rg * 4 + r;
        if (row >= n) break;
        float4 v;
        v.x = acc[r][0]; v.y = acc[r][1]; v.z = acc[r][2]; v.w = acc[r][3];
        *(float4*)(OUT + (size_t)row * 128 + cg * 4) = v;
    }
}

// ---------------- [n,128] @ [128,128] GEMM, 4x4 register tile ----------------
__global__ __launch_bounds__(256) void k_gemmT(
    const float* X, const float* __restrict__ W, float* OUT, int n)
{
    __shared__ float Xs[32][132];
    __shared__ float Ws[32][132];
    int t = threadIdx.x;
    int cg = t & 31, rg = t >> 5;
    int base = blockIdx.x * 32;

    #pragma unroll
    for (int h = 0; h < 4; h++) {
        int fi = t + h * 256;
        int row = fi >> 5, q = fi & 31;
        float4 v = {0.f, 0.f, 0.f, 0.f};
        if (base + row < n) v = *(const float4*)(X + (size_t)(base + row) * 128 + q * 4);
        *(float4*)&Xs[row][q * 4] = v;
    }

    float acc[4][4];
    #pragma unroll
    for (int r = 0; r < 4; r++)
        #pragma unroll
        for (int c = 0; c < 4; c++) acc[r][c] = 0.f;

    for (int kc = 0; kc < 128; kc += 32) {
        __syncthreads();
        #pragma unroll
        for (int h = 0; h < 4; h++) {
            int fi = t + h * 256;
            int k = fi >> 5, q = fi & 31;
            *(float4*)&Ws[k][q * 4] = *(const float4*)(W + (size_t)(kc + k) * 128 + q * 4);
        }
        __syncthreads();
        #pragma unroll
        for (int k4 = 0; k4 < 8; k4++) {
            int k = k4 * 4;
            float4 w0 = *(const float4*)&Ws[k + 0][cg * 4];
            float4 w1 = *(const float4*)&Ws[k + 1][cg * 4];
            float4 w2 = *(const float4*)&Ws[k + 2][cg * 4];
            float4 w3 = *(const float4*)&Ws[k + 3][cg * 4];
            #pragma unroll
            for (int r = 0; r < 4; r++) {
                float4 xv = *(const float4*)&Xs[rg * 4 + r][kc + k];
                acc[r][0] = fmaf(xv.w, w3.x, fmaf(xv.z, w2.x, fmaf(xv.y, w1.x, fmaf(xv.x, w0.x, acc[r][0]))));
                acc[r][1] = fmaf(xv.w, w3.y, fmaf(xv.z, w2.y, fmaf(xv.y, w1.y, fmaf(xv.x, w0.y, acc[r][1]))));
                acc[r][2] = fmaf(xv.w, w3.z, fmaf(xv.z, w2.z, fmaf(xv.y, w1.z, fmaf(xv.x, w0.z, acc[r][2]))));
                acc[r][3] = fmaf(xv.w, w3.w, fmaf(xv.z, w2.w, fmaf(xv.y, w1.w, fmaf(xv.x, w0.w, acc[r][3]))));
            }
        }
    }

    #pragma unroll
    for (int r = 0; r < 4; r++) {
        int row = base + rg * 4 + r;
        if (row >= n) break;
        float4 v;
        v.x = acc[r][0]; v.y = acc[r][1]; v.z = acc[r][2]; v.w = acc[r][3];
        *(float4*)(OUT + (size_t)row * 128 + cg * 4) = v;
    }
}

// ---------------- fused CSR build over 5 segments ----------------------------
__device__ __forceinline__ void seg_of_scanblk(int b, int& doff, int& bsoff, int& lb) {
    if (b < 196)      { doff = 0;      bsoff = 0;   lb = b; }
    else if (b < 245) { doff = 200704; bsoff = 196; lb = b - 196; }
    else if (b < 258) { doff = 250880; bsoff = 245; lb = b - 245; }
    else if (b < 307) { doff = 264192; bsoff = 258; lb = b - 258; }
    else              { doff = 314368; bsoff = 307; lb = b - 307; }
}

__global__ __launch_bounds__(256) void k_count_all(
    const int* __restrict__ d0, const int* __restrict__ d1, const int* __restrict__ d2,
    const int* __restrict__ p1, const int* __restrict__ p2,
    int* __restrict__ degs, int* __restrict__ ranks)
{
    int t0 = blockIdx.x * 256 + threadIdx.x;
    if (t0 >= 587500) return;
    #pragma unroll
    for (int k = 0; k < 4; k++) {
        int gid = t0 + k * 587500;
        int idx;
        if (gid < 1600000)      idx = d0[gid];
        else if (gid < 2000000) idx = 200704 + d1[gid - 1600000];
        else if (gid < 2100000) idx = 250880 + d2[gid - 2000000];
        else if (gid < 2300000) idx = 264192 + p1[gid - 2100000];
        else                    idx = 314368 + p2[gid - 2300000];
        ranks[gid] = atomicAdd(&degs[idx], 1);
    }
}

__global__ __launch_bounds__(256) void k_scan_all(
    const int* __restrict__ degs, int* __restrict__ rowsts, int* __restrict__ bsums)
{
    __shared__ int sh[256];
    int doff, bsoff, lb;
    seg_of_scanblk(blockIdx.x, doff, bsoff, lb);
    int t = threadIdx.x;
    int base = doff + lb * 1024 + t * 4;
    int v[4], s = 0;
    #pragma unroll
    for (int k = 0; k < 4; k++) { v[k] = degs[base + k]; s += v[k]; }
    sh[t] = s;
    __syncthreads();
    for (int off = 1; off < 256; off <<= 1) {
        int x = 0;
        if (t >= off) x = sh[t - off];
        __syncthreads();
        if (t >= off) sh[t] += x;
        __syncthreads();
    }
    int ex = sh[t] - s;
    if (t == 255) bsums[bsoff + lb] = sh[255];
    #pragma unroll
    for (int k = 0; k < 4; k++) { rowsts[base + k] = ex; ex += v[k]; }
}

// add block offsets (self-computed prefix of raw bsums) + dinv for segs 0-2
__global__ __launch_bounds__(256) void k_scanadd_all(
    int* __restrict__ rowsts, const int* __restrict__ bsums,
    const int* __restrict__ degs, float* __restrict__ dinvs)
{
    __shared__ int sh[256];
    int doff, bsoff, lb;
    seg_of_scanblk(blockIdx.x, doff, bsoff, lb);
    int t = threadIdx.x;
    sh[t] = (t < lb) ? bsums[bsoff + t] : 0;
    __syncthreads();
    #pragma unroll
    for (int off = 128; off >= 1; off >>= 1) {
        if (t < off) sh[t] += sh[t + off];
        __syncthreads();
    }
    int add = sh[0];
    int base = doff + lb * 1024 + t * 4;
    bool dodinv = (doff <= 250880);
    #pragma unroll
    for (int k = 0; k < 4; k++) {
        int i = base + k;
        rowsts[i] += add;
        if (dodinv) dinvs[i] = rsqrtf((float)degs[i] + 1.0f);
    }
}

// atomic-free scatter; edge segs also store per-edge src weight (dinv[src]),
// and seg0 resolves nodelist: elist[p] = nl[src]
__global__ __launch_bounds__(256) void k_scatter_all(
    const int* __restrict__ s0, const int* __restrict__ d0,
    const int* __restrict__ s1, const int* __restrict__ d1,
    const int* __restrict__ s2, const int* __restrict__ d2,
    const int* __restrict__ p1, const int* __restrict__ p2,
    const int* __restrict__ nl, const float* __restrict__ dinvs,
    const int* __restrict__ rowsts, const int* __restrict__ ranks,
    int* __restrict__ elists, float* __restrict__ edw)
{
    int t0 = blockIdx.x * 256 + threadIdx.x;
    if (t0 >= 587500) return;
    #pragma unroll
    for (int k = 0; k < 4; k++) {
        int gid = t0 + k * 587500;
        if (gid < 1600000) {
            int s = s0[gid];
            int p = rowsts[d0[gid]] + ranks[gid];
            elists[p] = nl[s];
            edw[p] = dinvs[s];
        } else if (gid < 2000000) {
            int i = gid - 1600000;
            int s = s1[i];
            int p = rowsts[200704 + d1[i]] + ranks[gid];
            elists[1600000 + p] = s;
            edw[1600000 + p] = dinvs[200704 + s];
        } else if (gid < 2100000) {
            int i = gid - 2000000;
            int s = s2[i];
            int p = rowsts[250880 + d2[i]] + ranks[gid];
            elists[2000000 + p] = s;
            edw[2000000 + p] = dinvs[250880 + s];
        } else if (gid < 2300000) {
            int i = gid - 2100000;
            int p = rowsts[264192 + p1[i]] + ranks[gid];
            elists[2100000 + p] = i;
        } else {
            int i = gid - 2300000;
            int p = rowsts[314368 + p2[i]] + ranks[gid];
            elists[2300000 + p] = i;
        }
    }
}

// ---------------- GCN pieces -------------------------------------------------
__global__ __launch_bounds__(256) void k_gatherU(
    const float* __restrict__ U, const int* __restrict__ nl,
    const int* __restrict__ rowst, const int* __restrict__ elist,
    const float* __restrict__ edw, const float* __restrict__ dinv,
    const float* __restrict__ bias, float* __restrict__ out, int n)
{
    size_t gid = (size_t)blockIdx.x * 256 + threadIdx.x;
    int d = (int)(gid >> 5);
    if (d >= n) return;
    int l = (int)(gid & 31);
    const float4* Uv = (const float4*)U;
    float dd = dinv[d];
    float4 self = Uv[(size_t)nl[d] * 32 + l];
    float4 acc;
    acc.x = self.x * dd; acc.y = self.y * dd; acc.z = self.z * dd; acc.w = self.w * dd;
    int s0 = rowst[d], s1 = rowst[d + 1];
    for (int e = s0; e < s1; ++e) {
        int srow = elist[e];
        float w = edw[e];
        float4 v = Uv[(size_t)srow * 32 + l];
        acc.x = fmaf(v.x, w, acc.x);
        acc.y = fmaf(v.y, w, acc.y);
        acc.z = fmaf(v.z, w, acc.z);
        acc.w = fmaf(v.w, w, acc.w);
    }
    const float4 b = ((const float4*)bias)[l];
    float4 y;
    y.x = fmaxf(fmaf(acc.x, dd, b.x), 0.f);
    y.y = fmaxf(fmaf(acc.y, dd, b.y), 0.f);
    y.z = fmaxf(fmaf(acc.z, dd, b.z), 0.f);
    y.w = fmaxf(fmaf(acc.w, dd, b.w), 0.f);
    ((float4*)out)[(size_t)d * 32 + l] = y;
}

__global__ __launch_bounds__(256) void k_gather(
    const float* __restrict__ h, const int* __restrict__ rowst,
    const int* __restrict__ elist, const float* __restrict__ edw,
    const float* __restrict__ dinv, const float* __restrict__ bias,
    float* __restrict__ out, int n)
{
    size_t gid = (size_t)blockIdx.x * 256 + threadIdx.x;
    int d = (int)(gid >> 5);
    if (d >= n) return;
    int l = (int)(gid & 31);
    const float4* hv = (const float4*)h;
    float dd = dinv[d];
    float4 self = hv[(size_t)d * 32 + l];
    float4 acc;
    acc.x = self.x * dd; acc.y = self.y * dd; acc.z = self.z * dd; acc.w = self.w * dd;
    int s0 = rowst[d], s1 = rowst[d + 1];
    for (int e = s0; e < s1; ++e) {
        int srow = elist[e];
        float w = edw[e];
        float4 v = hv[(size_t)srow * 32 + l];
        acc.x = fmaf(v.x, w, acc.x);
        acc.y = fmaf(v.y, w, acc.y);
        acc.z = fmaf(v.z, w, acc.z);
        acc.w = fmaf(v.w, w, acc.w);
    }
    const float4 b = ((const float4*)bias)[l];
    float4 y;
    y.x = fmaxf(fmaf(acc.x, dd, b.x), 0.f);
    y.y = fmaxf(fmaf(acc.y, dd, b.y), 0.f);
    y.z = fmaxf(fmaf(acc.z, dd, b.z), 0.f);
    y.w = fmaxf(fmaf(acc.w, dd, b.w), 0.f);
    ((float4*)out)[(size_t)d * 32 + l] = y;
}

__global__ __launch_bounds__(256) void k_poolgather(
    const float* __restrict__ Y, const int* __restrict__ rowst,
    const int* __restrict__ elist, float* __restrict__ out, int np)
{
    size_t gid = (size_t)blockIdx.x * 256 + threadIdx.x;
    int p = (int)(gid >> 5);
    if (p >= np) return;
    int l = (int)(gid & 31);
    const float4* yv = (const float4*)Y;
    float4 acc = {0.f, 0.f, 0.f, 0.f};
    int s0 = rowst[p], s1 = rowst[p + 1];
    for (int e = s0; e < s1; ++e) {
        int i = elist[e];
        float4 v = yv[(size_t)i * 32 + l];
        acc.x += v.x; acc.y += v.y; acc.z += v.z; acc.w += v.w;
    }
    float4 y;
    y.x = fmaxf(acc.x, 0.f); y.y = fmaxf(acc.y, 0.f);
    y.z = fmaxf(acc.z, 0.f); y.w = fmaxf(acc.w, 0.f);
    ((float4*)out)[(size_t)p * 32 + l] = y;
}

__global__ __launch_bounds__(128) void k_bpool_all(
    const float* __restrict__ X1, const float* __restrict__ X2, const float* __restrict__ Y2,
    const int* __restrict__ b1, const int* __restrict__ b2, float* __restrict__ pl)
{
    int b = blockIdx.x;
    const float* src; const int* bidx; int coloff, n, r0;
    if (b < 391)      { src = X1; bidx = b1; coloff = 0;   n = 50000; r0 = b * 128; }
    else if (b < 489) { src = X2; bidx = b2; coloff = 128; n = 12500; r0 = (b - 391) * 128; }
    else              { src = Y2; bidx = b2; coloff = 256; n = 12500; r0 = (b - 489) * 128; }
    if (r0 >= n) return;
    int j = threadIdx.x;
    int r1 = min(r0 + 128, n);
    float acc = 0.f;
    int prev = bidx[r0];
    for (int r = r0; r < r1; ++r) {
        int bb = bidx[r];
        if (bb != prev) {
            unsafeAtomicAdd(&pl[(size_t)prev * 384 + coloff + j], acc);
            acc = 0.f; prev = bb;
        }
        acc += src[(size_t)r * 128 + j];
    }
    unsafeAtomicAdd(&pl[(size_t)prev * 384 + coloff + j], acc);
}

// fused 2-layer MLP
__global__ void k_mlp2(const float* __restrict__ PL,
                       const float* __restrict__ Wc1, const float* __restrict__ bc1,
                       const float* __restrict__ Wc2, const float* __restrict__ bc2,
                       float* __restrict__ out)
{
    __shared__ float as[384];
    __shared__ float zs[128];
    int r = blockIdx.x, j = threadIdx.x;
    as[j] = PL[(size_t)r * 384 + j];
    as[j + 128] = PL[(size_t)r * 384 + 128 + j];
    as[j + 256] = PL[(size_t)r * 384 + 256 + j];
    __syncthreads();
    float acc = bc1[j];
    for (int k = 0; k < 384; k++) acc = fmaf(as[k], Wc1[(size_t)k * 128 + j], acc);
    zs[j] = fmaxf(acc, 0.f);
    __syncthreads();
    float o = bc2[j];
    for (int k = 0; k < 128; k++) o = fmaf(zs[k], Wc2[(size_t)k * 128 + j], o);
    out[(size_t)r * 128 + j] = o;
}

extern "C" void kernel_launch(void* const* d_in, const int* in_sizes, int n_in,
                              void* d_out, int out_size, void* d_ws, size_t ws_size,
                              hipStream_t stream)
{
    const float* x_raw  = (const float*)d_in[0];
    const float* W_des  = (const float*)d_in[1];
    const float* b_des  = (const float*)d_in[2];
    const float* W_twe  = (const float*)d_in[3];
    const float* b_twe  = (const float*)d_in[4];
    const float* W_num  = (const float*)d_in[5];
    const float* b_num  = (const float*)d_in[6];
    const float* W_cat  = (const float*)d_in[7];
    const float* b_cat  = (const float*)d_in[8];
    const float* W_in   = (const float*)d_in[9];
    const float* b_in   = (const float*)d_in[10];
    const float* prelua = (const float*)d_in[11];
    const float* W_conv = (const float*)d_in[12];
    const float* b_conv = (const float*)d_in[13];
    const float* Wc1    = (const float*)d_in[14];
    const float* bc1    = (const float*)d_in[15];
    const float* Wc2    = (const float*)d_in[16];
    const float* bc2    = (const float*)d_in[17];
    const int* nodelist = (const int*)d_in[18];
    const int* e0       = (const int*)d_in[19];
    const int* e1       = (const int*)d_in[20];
    const int* e2       = (const int*)d_in[21];
    const int* parent1  = (const int*)d_in[22];
    const int* parent2  = (const int*)d_in[23];
    const int* batch1   = (const int*)d_in[24];
    const int* batch2   = (const int*)d_in[25];

    // ---- workspace layout ----
    float* WS  = (float*)d_ws;
    float* ENC = WS;                    // 50000*128; dead after k_gemm2
    int*   DEGS   = (int*)d_ws;                 // 327680
    int*   ROWSTS = DEGS + 327680;              // 327680
    float* DINVS  = (float*)(ROWSTS + 327680);  // 264192
    int*   BSUMS  = (int*)(DINVS + 264192);     // 512
    int*   RANKS  = BSUMS + 512;                // 2350000
    int*   ELISTS = RANKS + 2350000;            // 2350000
    float* U  = WS + 6400000;           // 50000*128
    float* H  = WS + 12800000;          // 50000*128
    float* Y  = WS + 19200000;          // 200000*128
    float* X1 = WS + 44800000;          // 50000*128
    float* X2 = WS + 51200000;          // 12500*128
    float* PL = WS + 52800000;          // 128*384
    float* EDW = WS + 52900000;         // 2100000 per-edge src weights

    hipMemsetAsync(PL, 0, (size_t)128 * 384 * 4, stream);

    // ---- encoder -> ENC; U = prelu(ENC@W_in+b)@W_conv0 (fused) ----
    k_enc3<<<(N_USERS + 63) / 64, 256, 0, stream>>>(
        x_raw, W_des, b_des, W_twe, b_twe, W_num, b_num, W_cat, b_cat, ENC);
    k_gemm2<<<(N_USERS + 31) / 32, 256, 0, stream>>>(
        ENC, W_in, b_in, prelua, W_conv, U, N_USERS);

    // ---- fused CSR builds (+dinv, +edge weights); clobbers ENC (dead) ----
    hipMemsetAsync(DEGS, 0, (size_t)327680 * 4, stream);
    k_count_all<<<(587500 + 255) / 256, 256, 0, stream>>>(
        e0 + EE0, e1 + EE1, e2 + EE2, parent1, parent2, DEGS, RANKS);
    k_scan_all<<<320, 256, 0, stream>>>(DEGS, ROWSTS, BSUMS);
    k_scanadd_all<<<320, 256, 0, stream>>>(ROWSTS, BSUMS, DEGS, DINVS);
    k_scatter_all<<<(587500 + 255) / 256, 256, 0, stream>>>(
        e0, e0 + EE0, e1, e1 + EE1, e2, e2 + EE2, parent1, parent2,
        nodelist, DINVS, ROWSTS, RANKS, ELISTS, EDW);

    // ---- layer 0: GCN over NN0 -> Y; pool -> X1 ----
    k_gatherU<<<(int)(((size_t)NN0 * 32 + 255) / 256), 256, 0, stream>>>(
        U, nodelist, ROWSTS, ELISTS, EDW, DINVS, b_conv, Y, NN0);
    k_poolgather<<<(int)(((size_t)NN1 * 32 + 255) / 256), 256, 0, stream>>>(
        Y, ROWSTS + 264192, ELISTS + 2100000, X1, NN1);

    // ---- layer 1 ----
    k_gemmT<<<(NN1 + 31) / 32, 256, 0, stream>>>(X1, W_conv + 16384, H, NN1);
    k_gather<<<(int)(((size_t)NN1 * 32 + 255) / 256), 256, 0, stream>>>(
        H, ROWSTS + 200704, ELISTS + 1600000, EDW + 1600000, DINVS + 200704,
        b_conv + 128, Y, NN1);
    k_poolgather<<<(int)(((size_t)NN2 * 32 + 255) / 256), 256, 0, stream>>>(
        Y, ROWSTS + 314368, ELISTS + 2300000, X2, NN2);

    // ---- layer 2 ----
    k_gemmT<<<(NN2 + 31) / 32, 256, 0, stream>>>(X2, W_conv + 32768, H, NN2);
    k_gather<<<(int)(((size_t)NN2 * 32 + 255) / 256), 256, 0, stream>>>(
        H, ROWSTS + 250880, ELISTS + 2000000, EDW + 2000000, DINVS + 250880,
        b_conv + 256, Y, NN2);

    // ---- batch pooling (fused, sorted keys) ----
    k_bpool_all<<<587, 128, 0, stream>>>(X1, X2, Y, batch1, batch2, PL);

    // ---- final fused MLP ----
    k_mlp2<<<128, 128, 0, stream>>>(PL, Wc1, bc1, Wc2, bc2, (float*)d_out);
}

// Round 11
// 718.064 us; speedup vs baseline: 1.1818x; 1.0522x over previous
//
#include <hip/hip_runtime.h>

#define N_USERS 50000
#define NN0 200000
#define NN1 50000
#define NN2 12500
#define EE0 1600000
#define EE1 400000
#define EE2 100000

// Padded segment geometry for fused CSR builds (padded to 1024 multiples):
// seg:      0:e0        1:e1      2:e2      3:parent1  4:parent2
// deg off:  0           200704    250880    264192     314368   (total 327680)
// scan blk: 196         49        13        49         13       (cum 196,245,258,307,320)
// bsum off: 0           196       245       258        307
// el off:   0           1600000   2000000   2100000    2300000

// ---------------- encoder: h128[r] = leaky([d|t|n|c]) -------------------------
// 64 rows x 64 heavy cols; thread = 4 rows x 4 cols.
// Staging: 16 rows x 4 q per instruction -> 64B/row coalesced global loads,
// 2 lanes/bank LDS stores. XsT plane at +2192 floats (bank offset 16) so
// des/tweet compute reads use disjoint bank halves.
__global__ __launch_bounds__(256) void k_enc3(
    const float* __restrict__ xr,
    const float* __restrict__ Wd, const float* __restrict__ bd,
    const float* __restrict__ Wt, const float* __restrict__ bt,
    const float* __restrict__ Wn, const float* __restrict__ bn,
    const float* __restrict__ Wc, const float* __restrict__ bc,
    float* __restrict__ h128)
{
    __shared__ float XsB[4368];    // [0,2176): des [k][row]; [2192,4368): tweet
    __shared__ float Ws[32][68];   // [k][col 0..63] = [Wd|Wt]
    __shared__ float xnc[64][8];
    __shared__ float Wl[8][64];

    int t = threadIdx.x;
    int lane = t & 63, wv = t >> 6;
    int cg = t & 15, rg = t >> 4;
    int base = blockIdx.x * 64;

    if (t < 64) {
        int row = base + t;
        if (row < N_USERS) {
            const float* xp = xr + (size_t)row * 1544;
            float4 a = *(const float4*)xp;
            float2 b2 = *(const float2*)(xp + 4);
            float2 c2 = *(const float2*)(xp + 774);
            xnc[t][0] = a.x; xnc[t][1] = a.y; xnc[t][2] = a.z; xnc[t][3] = a.w;
            xnc[t][4] = b2.x; xnc[t][5] = b2.y; xnc[t][6] = c2.x; xnc[t][7] = c2.y;
        } else {
            #pragma unroll
            for (int k = 0; k < 8; k++) xnc[t][k] = 0.f;
        }
    } else if (t >= 192) {
        int l = t - 192;
        #pragma unroll
        for (int k = 0; k < 8; k++) {
            float w = 0.f;
            if (l < 32) { if (k < 6) w = Wn[k * 32 + l]; }
            else        { if (k >= 6) w = Wc[(k - 6) * 32 + (l - 32)]; }
            Wl[k][l] = w;
        }
    }

    // staging geometry (constant per thread)
    int srow = (lane & 15) + wv * 16;      // 16 rows x 4 waves
    int grow = base + srow;
    bool vrow = grow < N_USERS;
    const float* xrow = xr + (size_t)grow * 1544;

    float acc[4][4];
    #pragma unroll
    for (int r = 0; r < 4; r++)
        #pragma unroll
        for (int c = 0; c < 4; c++) acc[r][c] = 0.f;

    for (int kc = 0; kc < 768; kc += 32) {
        __syncthreads();
        // stage X: per instruction 16 rows x 4 q -> coalesced 64B/row loads;
        // transposed b32 stores land 2 lanes/bank (free)
        #pragma unroll
        for (int h = 0; h < 2; h++) {
            int q = (lane >> 4) + h * 4;   // 0..7
            float4 vd = {0.f, 0.f, 0.f, 0.f};
            float2 va = {0.f, 0.f}, vb = {0.f, 0.f};
            if (vrow) {
                const float* xp = xrow + kc + q * 4;
                vd = *(const float4*)(xp + 776);  // 16B aligned
                va = *(const float2*)(xp + 6);    // 8B aligned
                vb = *(const float2*)(xp + 8);
            }
            int k0 = q * 4;
            XsB[(k0 + 0) * 68 + srow] = vd.x;
            XsB[(k0 + 1) * 68 + srow] = vd.y;
            XsB[(k0 + 2) * 68 + srow] = vd.z;
            XsB[(k0 + 3) * 68 + srow] = vd.w;
            XsB[2192 + (k0 + 0) * 68 + srow] = va.x;
            XsB[2192 + (k0 + 1) * 68 + srow] = va.y;
            XsB[2192 + (k0 + 2) * 68 + srow] = vb.x;
            XsB[2192 + (k0 + 3) * 68 + srow] = vb.y;
        }
        // stage W chunk [32k][64c] (512 float4 = 2 x 256)
        #pragma unroll
        for (int h = 0; h < 2; h++) {
            int fi = t + h * 256;
            int k = fi >> 4, c4 = (fi & 15) * 4;
            float4 w = (c4 < 32) ? *(const float4*)(Wd + (size_t)(kc + k) * 32 + c4)
                                 : *(const float4*)(Wt + (size_t)(kc + k) * 32 + (c4 - 32));
            *(float4*)&Ws[k][c4] = w;
        }
        __syncthreads();

        const float* Xp = (cg < 8) ? XsB : (XsB + 2192);
        #pragma unroll 8
        for (int k = 0; k < 32; k++) {
            float4 xv = *(const float4*)(Xp + k * 68 + rg * 4);
            float4 wv2 = *(const float4*)&Ws[k][cg * 4];
            acc[0][0] = fmaf(xv.x, wv2.x, acc[0][0]);
            acc[0][1] = fmaf(xv.x, wv2.y, acc[0][1]);
            acc[0][2] = fmaf(xv.x, wv2.z, acc[0][2]);
            acc[0][3] = fmaf(xv.x, wv2.w, acc[0][3]);
            acc[1][0] = fmaf(xv.y, wv2.x, acc[1][0]);
            acc[1][1] = fmaf(xv.y, wv2.y, acc[1][1]);
            acc[1][2] = fmaf(xv.y, wv2.z, acc[1][2]);
            acc[1][3] = fmaf(xv.y, wv2.w, acc[1][3]);
            acc[2][0] = fmaf(xv.z, wv2.x, acc[2][0]);
            acc[2][1] = fmaf(xv.z, wv2.y, acc[2][1]);
            acc[2][2] = fmaf(xv.z, wv2.z, acc[2][2]);
            acc[2][3] = fmaf(xv.z, wv2.w, acc[2][3]);
            acc[3][0] = fmaf(xv.w, wv2.x, acc[3][0]);
            acc[3][1] = fmaf(xv.w, wv2.y, acc[3][1]);
            acc[3][2] = fmaf(xv.w, wv2.z, acc[3][2]);
            acc[3][3] = fmaf(xv.w, wv2.w, acc[3][3]);
        }
    }

    float bh[4], bl[4], wlv[8][4];
    #pragma unroll
    for (int c = 0; c < 4; c++) {
        int j = cg * 4 + c;
        bh[c] = (j < 32) ? bd[j] : bt[j - 32];
        bl[c] = (j < 32) ? bn[j] : bc[j - 32];
        #pragma unroll
        for (int k = 0; k < 8; k++) wlv[k][c] = Wl[k][j];
    }
    #pragma unroll
    for (int r = 0; r < 4; r++) {
        int lr = rg * 4 + r;
        int row = base + lr;
        if (row >= N_USERS) break;
        float4 hv;
        float* ph = &hv.x;
        #pragma unroll
        for (int c = 0; c < 4; c++) {
            float v = acc[r][c] + bh[c];
            ph[c] = v > 0.f ? v : 0.01f * v;
        }
        *(float4*)(h128 + (size_t)row * 128 + cg * 4) = hv;
        float4 lv;
        float* pl = &lv.x;
        #pragma unroll
        for (int c = 0; c < 4; c++) {
            float v = bl[c];
            #pragma unroll
            for (int k = 0; k < 8; k++) v = fmaf(xnc[lr][k], wlv[k][c], v);
            pl[c] = v > 0.f ? v : 0.01f * v;
        }
        *(float4*)(h128 + (size_t)row * 128 + 64 + cg * 4) = lv;
    }
}

// ---------------- fused dual GEMM: U = (prelu(X@W1+b1)) @ W2 -----------------
__global__ __launch_bounds__(256) void k_gemm2(
    const float* __restrict__ X, const float* __restrict__ W1,
    const float* __restrict__ b1, const float* __restrict__ pa,
    const float* __restrict__ W2, float* __restrict__ OUT, int n)
{
    __shared__ float Xs[32][132];
    __shared__ float Ws[32][132];
    int t = threadIdx.x;
    int cg = t & 31, rg = t >> 5;
    int base = blockIdx.x * 32;

    #pragma unroll
    for (int h = 0; h < 4; h++) {
        int fi = t + h * 256;
        int row = fi >> 5, q = fi & 31;
        float4 v = {0.f, 0.f, 0.f, 0.f};
        if (base + row < n) v = *(const float4*)(X + (size_t)(base + row) * 128 + q * 4);
        *(float4*)&Xs[row][q * 4] = v;
    }

    float acc[4][4];
    #pragma unroll
    for (int r = 0; r < 4; r++)
        #pragma unroll
        for (int c = 0; c < 4; c++) acc[r][c] = 0.f;

    for (int kc = 0; kc < 128; kc += 32) {
        __syncthreads();
        #pragma unroll
        for (int h = 0; h < 4; h++) {
            int fi = t + h * 256;
            int k = fi >> 5, q = fi & 31;
            *(float4*)&Ws[k][q * 4] = *(const float4*)(W1 + (size_t)(kc + k) * 128 + q * 4);
        }
        __syncthreads();
        #pragma unroll
        for (int k4 = 0; k4 < 8; k4++) {
            int k = k4 * 4;
            float4 w0 = *(const float4*)&Ws[k + 0][cg * 4];
            float4 w1 = *(const float4*)&Ws[k + 1][cg * 4];
            float4 w2 = *(const float4*)&Ws[k + 2][cg * 4];
            float4 w3 = *(const float4*)&Ws[k + 3][cg * 4];
            #pragma unroll
            for (int r = 0; r < 4; r++) {
                float4 xv = *(const float4*)&Xs[rg * 4 + r][kc + k];
                acc[r][0] = fmaf(xv.w, w3.x, fmaf(xv.z, w2.x, fmaf(xv.y, w1.x, fmaf(xv.x, w0.x, acc[r][0]))));
                acc[r][1] = fmaf(xv.w, w3.y, fmaf(xv.z, w2.y, fmaf(xv.y, w1.y, fmaf(xv.x, w0.y, acc[r][1]))));
                acc[r][2] = fmaf(xv.w, w3.z, fmaf(xv.z, w2.z, fmaf(xv.y, w1.z, fmaf(xv.x, w0.z, acc[r][2]))));
                acc[r][3] = fmaf(xv.w, w3.w, fmaf(xv.z, w2.w, fmaf(xv.y, w1.w, fmaf(xv.x, w0.w, acc[r][3]))));
            }
        }
    }

    float4 bv = *(const float4*)(b1 + cg * 4);
    float4 pv = *(const float4*)(pa + cg * 4);
    __syncthreads();
    #pragma unroll
    for (int r = 0; r < 4; r++) {
        float v0 = acc[r][0] + bv.x; v0 = v0 > 0.f ? v0 : pv.x * v0;
        float v1 = acc[r][1] + bv.y; v1 = v1 > 0.f ? v1 : pv.y * v1;
        float v2 = acc[r][2] + bv.z; v2 = v2 > 0.f ? v2 : pv.z * v2;
        float v3 = acc[r][3] + bv.w; v3 = v3 > 0.f ? v3 : pv.w * v3;
        Xs[rg * 4 + r][cg * 4 + 0] = v0;
        Xs[rg * 4 + r][cg * 4 + 1] = v1;
        Xs[rg * 4 + r][cg * 4 + 2] = v2;
        Xs[rg * 4 + r][cg * 4 + 3] = v3;
        acc[r][0] = 0.f; acc[r][1] = 0.f; acc[r][2] = 0.f; acc[r][3] = 0.f;
    }

    for (int kc = 0; kc < 128; kc += 32) {
        __syncthreads();
        #pragma unroll
        for (int h = 0; h < 4; h++) {
            int fi = t + h * 256;
            int k = fi >> 5, q = fi & 31;
            *(float4*)&Ws[k][q * 4] = *(const float4*)(W2 + (size_t)(kc + k) * 128 + q * 4);
        }
        __syncthreads();
        #pragma unroll
        for (int k4 = 0; k4 < 8; k4++) {
            int k = k4 * 4;
            float4 w0 = *(const float4*)&Ws[k + 0][cg * 4];
            float4 w1 = *(const float4*)&Ws[k + 1][cg * 4];
            float4 w2 = *(const float4*)&Ws[k + 2][cg * 4];
            float4 w3 = *(const float4*)&Ws[k + 3][cg * 4];
            #pragma unroll
            for (int r = 0; r < 4; r++) {
                float4 xv = *(const float4*)&Xs[rg * 4 + r][kc + k];
                acc[r][0] = fmaf(xv.w, w3.x, fmaf(xv.z, w2.x, fmaf(xv.y, w1.x, fmaf(xv.x, w0.x, acc[r][0]))));
                acc[r][1] = fmaf(xv.w, w3.y, fmaf(xv.z, w2.y, fmaf(xv.y, w1.y, fmaf(xv.x, w0.y, acc[r][1]))));
                acc[r][2] = fmaf(xv.w, w3.z, fmaf(xv.z, w2.z, fmaf(xv.y, w1.z, fmaf(xv.x, w0.z, acc[r][2]))));
                acc[r][3] = fmaf(xv.w, w3.w, fmaf(xv.z, w2.w, fmaf(xv.y, w1.w, fmaf(xv.x, w0.w, acc[r][3]))));
            }
        }
    }

    #pragma unroll
    for (int r = 0; r < 4; r++) {
        int row = base + rg * 4 + r;
        if (row >= n) break;
        float4 v;
        v.x = acc[r][0]; v.y = acc[r][1]; v.z = acc[r][2]; v.w = acc[r][3];
        *(float4*)(OUT + (size_t)row * 128 + cg * 4) = v;
    }
}

// ---------------- [n,128] @ [128,128] GEMM, 4x4 register tile ----------------
__global__ __launch_bounds__(256) void k_gemmT(
    const float* X, const float* __restrict__ W, float* OUT, int n)
{
    __shared__ float Xs[32][132];
    __shared__ float Ws[32][132];
    int t = threadIdx.x;
    int cg = t & 31, rg = t >> 5;
    int base = blockIdx.x * 32;

    #pragma unroll
    for (int h = 0; h < 4; h++) {
        int fi = t + h * 256;
        int row = fi >> 5, q = fi & 31;
        float4 v = {0.f, 0.f, 0.f, 0.f};
        if (base + row < n) v = *(const float4*)(X + (size_t)(base + row) * 128 + q * 4);
        *(float4*)&Xs[row][q * 4] = v;
    }

    float acc[4][4];
    #pragma unroll
    for (int r = 0; r < 4; r++)
        #pragma unroll
        for (int c = 0; c < 4; c++) acc[r][c] = 0.f;

    for (int kc = 0; kc < 128; kc += 32) {
        __syncthreads();
        #pragma unroll
        for (int h = 0; h < 4; h++) {
            int fi = t + h * 256;
            int k = fi >> 5, q = fi & 31;
            *(float4*)&Ws[k][q * 4] = *(const float4*)(W + (size_t)(kc + k) * 128 + q * 4);
        }
        __syncthreads();
        #pragma unroll
        for (int k4 = 0; k4 < 8; k4++) {
            int k = k4 * 4;
            float4 w0 = *(const float4*)&Ws[k + 0][cg * 4];
            float4 w1 = *(const float4*)&Ws[k + 1][cg * 4];
            float4 w2 = *(const float4*)&Ws[k + 2][cg * 4];
            float4 w3 = *(const float4*)&Ws[k + 3][cg * 4];
            #pragma unroll
            for (int r = 0; r < 4; r++) {
                float4 xv = *(const float4*)&Xs[rg * 4 + r][kc + k];
                acc[r][0] = fmaf(xv.w, w3.x, fmaf(xv.z, w2.x, fmaf(xv.y, w1.x, fmaf(xv.x, w0.x, acc[r][0]))));
                acc[r][1] = fmaf(xv.w, w3.y, fmaf(xv.z, w2.y, fmaf(xv.y, w1.y, fmaf(xv.x, w0.y, acc[r][1]))));
                acc[r][2] = fmaf(xv.w, w3.z, fmaf(xv.z, w2.z, fmaf(xv.y, w1.z, fmaf(xv.x, w0.z, acc[r][2]))));
                acc[r][3] = fmaf(xv.w, w3.w, fmaf(xv.z, w2.w, fmaf(xv.y, w1.w, fmaf(xv.x, w0.w, acc[r][3]))));
            }
        }
    }

    #pragma unroll
    for (int r = 0; r < 4; r++) {
        int row = base + rg * 4 + r;
        if (row >= n) break;
        float4 v;
        v.x = acc[r][0]; v.y = acc[r][1]; v.z = acc[r][2]; v.w = acc[r][3];
        *(float4*)(OUT + (size_t)row * 128 + cg * 4) = v;
    }
}

// ---------------- fused CSR build over 5 segments ----------------------------
__device__ __forceinline__ void seg_of_scanblk(int b, int& doff, int& bsoff, int& lb) {
    if (b < 196)      { doff = 0;      bsoff = 0;   lb = b; }
    else if (b < 245) { doff = 200704; bsoff = 196; lb = b - 196; }
    else if (b < 258) { doff = 250880; bsoff = 245; lb = b - 245; }
    else if (b < 307) { doff = 264192; bsoff = 258; lb = b - 258; }
    else              { doff = 314368; bsoff = 307; lb = b - 307; }
}

__global__ __launch_bounds__(256) void k_count_all(
    const int* __restrict__ d0, const int* __restrict__ d1, const int* __restrict__ d2,
    const int* __restrict__ p1, const int* __restrict__ p2,
    int* __restrict__ degs, int* __restrict__ ranks)
{
    int t0 = blockIdx.x * 256 + threadIdx.x;
    if (t0 >= 587500) return;
    #pragma unroll
    for (int k = 0; k < 4; k++) {
        int gid = t0 + k * 587500;
        int idx;
        if (gid < 1600000)      idx = d0[gid];
        else if (gid < 2000000) idx = 200704 + d1[gid - 1600000];
        else if (gid < 2100000) idx = 250880 + d2[gid - 2000000];
        else if (gid < 2300000) idx = 264192 + p1[gid - 2100000];
        else                    idx = 314368 + p2[gid - 2300000];
        ranks[gid] = atomicAdd(&degs[idx], 1);
    }
}

__global__ __launch_bounds__(256) void k_scan_all(
    const int* __restrict__ degs, int* __restrict__ rowsts, int* __restrict__ bsums)
{
    __shared__ int sh[256];
    int doff, bsoff, lb;
    seg_of_scanblk(blockIdx.x, doff, bsoff, lb);
    int t = threadIdx.x;
    int base = doff + lb * 1024 + t * 4;
    int v[4], s = 0;
    #pragma unroll
    for (int k = 0; k < 4; k++) { v[k] = degs[base + k]; s += v[k]; }
    sh[t] = s;
    __syncthreads();
    for (int off = 1; off < 256; off <<= 1) {
        int x = 0;
        if (t >= off) x = sh[t - off];
        __syncthreads();
        if (t >= off) sh[t] += x;
        __syncthreads();
    }
    int ex = sh[t] - s;
    if (t == 255) bsums[bsoff + lb] = sh[255];
    #pragma unroll
    for (int k = 0; k < 4; k++) { rowsts[base + k] = ex; ex += v[k]; }
}

// add block offsets (self-computed prefix of raw bsums) + dinv for segs 0-2
__global__ __launch_bounds__(256) void k_scanadd_all(
    int* __restrict__ rowsts, const int* __restrict__ bsums,
    const int* __restrict__ degs, float* __restrict__ dinvs)
{
    __shared__ int sh[256];
    int doff, bsoff, lb;
    seg_of_scanblk(blockIdx.x, doff, bsoff, lb);
    int t = threadIdx.x;
    sh[t] = (t < lb) ? bsums[bsoff + t] : 0;
    __syncthreads();
    #pragma unroll
    for (int off = 128; off >= 1; off >>= 1) {
        if (t < off) sh[t] += sh[t + off];
        __syncthreads();
    }
    int add = sh[0];
    int base = doff + lb * 1024 + t * 4;
    bool dodinv = (doff <= 250880);
    #pragma unroll
    for (int k = 0; k < 4; k++) {
        int i = base + k;
        rowsts[i] += add;
        if (dodinv) dinvs[i] = rsqrtf((float)degs[i] + 1.0f);
    }
}

// atomic-free scatter; edge segs also store per-edge src weight (dinv[src]),
// and seg0 resolves nodelist: elist[p] = nl[src]
__global__ __launch_bounds__(256) void k_scatter_all(
    const int* __restrict__ s0, const int* __restrict__ d0,
    const int* __restrict__ s1, const int* __restrict__ d1,
    const int* __restrict__ s2, const int* __restrict__ d2,
    const int* __restrict__ p1, const int* __restrict__ p2,
    const int* __restrict__ nl, const float* __restrict__ dinvs,
    const int* __restrict__ rowsts, const int* __restrict__ ranks,
    int* __restrict__ elists, float* __restrict__ edw)
{
    int t0 = blockIdx.x * 256 + threadIdx.x;
    if (t0 >= 587500) return;
    #pragma unroll
    for (int k = 0; k < 4; k++) {
        int gid = t0 + k * 587500;
        if (gid < 1600000) {
            int s = s0[gid];
            int p = rowsts[d0[gid]] + ranks[gid];
            elists[p] = nl[s];
            edw[p] = dinvs[s];
        } else if (gid < 2000000) {
            int i = gid - 1600000;
            int s = s1[i];
            int p = rowsts[200704 + d1[i]] + ranks[gid];
            elists[1600000 + p] = s;
            edw[1600000 + p] = dinvs[200704 + s];
        } else if (gid < 2100000) {
            int i = gid - 2000000;
            int s = s2[i];
            int p = rowsts[250880 + d2[i]] + ranks[gid];
            elists[2000000 + p] = s;
            edw[2000000 + p] = dinvs[250880 + s];
        } else if (gid < 2300000) {
            int i = gid - 2100000;
            int p = rowsts[264192 + p1[i]] + ranks[gid];
            elists[2100000 + p] = i;
        } else {
            int i = gid - 2300000;
            int p = rowsts[314368 + p2[i]] + ranks[gid];
            elists[2300000 + p] = i;
        }
    }
}

// ---------------- GCN pieces -------------------------------------------------
__global__ __launch_bounds__(256) void k_gatherU(
    const float* __restrict__ U, const int* __restrict__ nl,
    const int* __restrict__ rowst, const int* __restrict__ elist,
    const float* __restrict__ edw, const float* __restrict__ dinv,
    const float* __restrict__ bias, float* __restrict__ out, int n)
{
    size_t gid = (size_t)blockIdx.x * 256 + threadIdx.x;
    int d = (int)(gid >> 5);
    if (d >= n) return;
    int l = (int)(gid & 31);
    const float4* Uv = (const float4*)U;
    float dd = dinv[d];
    float4 self = Uv[(size_t)nl[d] * 32 + l];
    float4 acc;
    acc.x = self.x * dd; acc.y = self.y * dd; acc.z = self.z * dd; acc.w = self.w * dd;
    int s0 = rowst[d], s1 = rowst[d + 1];
    for (int e = s0; e < s1; ++e) {
        int srow = elist[e];
        float w = edw[e];
        float4 v = Uv[(size_t)srow * 32 + l];
        acc.x = fmaf(v.x, w, acc.x);
        acc.y = fmaf(v.y, w, acc.y);
        acc.z = fmaf(v.z, w, acc.z);
        acc.w = fmaf(v.w, w, acc.w);
    }
    const float4 b = ((const float4*)bias)[l];
    float4 y;
    y.x = fmaxf(fmaf(acc.x, dd, b.x), 0.f);
    y.y = fmaxf(fmaf(acc.y, dd, b.y), 0.f);
    y.z = fmaxf(fmaf(acc.z, dd, b.z), 0.f);
    y.w = fmaxf(fmaf(acc.w, dd, b.w), 0.f);
    ((float4*)out)[(size_t)d * 32 + l] = y;
}

__global__ __launch_bounds__(256) void k_gather(
    const float* __restrict__ h, const int* __restrict__ rowst,
    const int* __restrict__ elist, const float* __restrict__ edw,
    const float* __restrict__ dinv, const float* __restrict__ bias,
    float* __restrict__ out, int n)
{
    size_t gid = (size_t)blockIdx.x * 256 + threadIdx.x;
    int d = (int)(gid >> 5);
    if (d >= n) return;
    int l = (int)(gid & 31);
    const float4* hv = (const float4*)h;
    float dd = dinv[d];
    float4 self = hv[(size_t)d * 32 + l];
    float4 acc;
    acc.x = self.x * dd; acc.y = self.y * dd; acc.z = self.z * dd; acc.w = self.w * dd;
    int s0 = rowst[d], s1 = rowst[d + 1];
    for (int e = s0; e < s1; ++e) {
        int srow = elist[e];
        float w = edw[e];
        float4 v = hv[(size_t)srow * 32 + l];
        acc.x = fmaf(v.x, w, acc.x);
        acc.y = fmaf(v.y, w, acc.y);
        acc.z = fmaf(v.z, w, acc.z);
        acc.w = fmaf(v.w, w, acc.w);
    }
    const float4 b = ((const float4*)bias)[l];
    float4 y;
    y.x = fmaxf(fmaf(acc.x, dd, b.x), 0.f);
    y.y = fmaxf(fmaf(acc.y, dd, b.y), 0.f);
    y.z = fmaxf(fmaf(acc.z, dd, b.z), 0.f);
    y.w = fmaxf(fmaf(acc.w, dd, b.w), 0.f);
    ((float4*)out)[(size_t)d * 32 + l] = y;
}

__global__ __launch_bounds__(256) void k_poolgather(
    const float* __restrict__ Y, const int* __restrict__ rowst,
    const int* __restrict__ elist, float* __restrict__ out, int np)
{
    size_t gid = (size_t)blockIdx.x * 256 + threadIdx.x;
    int p = (int)(gid >> 5);
    if (p >= np) return;
    int l = (int)(gid & 31);
    const float4* yv = (const float4*)Y;
    float4 acc = {0.f, 0.f, 0.f, 0.f};
    int s0 = rowst[p], s1 = rowst[p + 1];
    for (int e = s0; e < s1; ++e) {
        int i = elist[e];
        float4 v = yv[(size_t)i * 32 + l];
        acc.x += v.x; acc.y += v.y; acc.z += v.z; acc.w += v.w;
    }
    float4 y;
    y.x = fmaxf(acc.x, 0.f); y.y = fmaxf(acc.y, 0.f);
    y.z = fmaxf(acc.z, 0.f); y.w = fmaxf(acc.w, 0.f);
    ((float4*)out)[(size_t)p * 32 + l] = y;
}

__global__ __launch_bounds__(128) void k_bpool_all(
    const float* __restrict__ X1, const float* __restrict__ X2, const float* __restrict__ Y2,
    const int* __restrict__ b1, const int* __restrict__ b2, float* __restrict__ pl)
{
    int b = blockIdx.x;
    const float* src; const int* bidx; int coloff, n, r0;
    if (b < 391)      { src = X1; bidx = b1; coloff = 0;   n = 50000; r0 = b * 128; }
    else if (b < 489) { src = X2; bidx = b2; coloff = 128; n = 12500; r0 = (b - 391) * 128; }
    else              { src = Y2; bidx = b2; coloff = 256; n = 12500; r0 = (b - 489) * 128; }
    if (r0 >= n) return;
    int j = threadIdx.x;
    int r1 = min(r0 + 128, n);
    float acc = 0.f;
    int prev = bidx[r0];
    for (int r = r0; r < r1; ++r) {
        int bb = bidx[r];
        if (bb != prev) {
            unsafeAtomicAdd(&pl[(size_t)prev * 384 + coloff + j], acc);
            acc = 0.f; prev = bb;
        }
        acc += src[(size_t)r * 128 + j];
    }
    unsafeAtomicAdd(&pl[(size_t)prev * 384 + coloff + j], acc);
}

// fused 2-layer MLP
__global__ void k_mlp2(const float* __restrict__ PL,
                       const float* __restrict__ Wc1, const float* __restrict__ bc1,
                       const float* __restrict__ Wc2, const float* __restrict__ bc2,
                       float* __restrict__ out)
{
    __shared__ float as[384];
    __shared__ float zs[128];
    int r = blockIdx.x, j = threadIdx.x;
    as[j] = PL[(size_t)r * 384 + j];
    as[j + 128] = PL[(size_t)r * 384 + 128 + j];
    as[j + 256] = PL[(size_t)r * 384 + 256 + j];
    __syncthreads();
    float acc = bc1[j];
    for (int k = 0; k < 384; k++) acc = fmaf(as[k], Wc1[(size_t)k * 128 + j], acc);
    zs[j] = fmaxf(acc, 0.f);
    __syncthreads();
    float o = bc2[j];
    for (int k = 0; k < 128; k++) o = fmaf(zs[k], Wc2[(size_t)k * 128 + j], o);
    out[(size_t)r * 128 + j] = o;
}

extern "C" void kernel_launch(void* const* d_in, const int* in_sizes, int n_in,
                              void* d_out, int out_size, void* d_ws, size_t ws_size,
                              hipStream_t stream)
{
    const float* x_raw  = (const float*)d_in[0];
    const float* W_des  = (const float*)d_in[1];
    const float* b_des  = (const float*)d_in[2];
    const float* W_twe  = (const float*)d_in[3];
    const float* b_twe  = (const float*)d_in[4];
    const float* W_num  = (const float*)d_in[5];
    const float* b_num  = (const float*)d_in[6];
    const float* W_cat  = (const float*)d_in[7];
    const float* b_cat  = (const float*)d_in[8];
    const float* W_in   = (const float*)d_in[9];
    const float* b_in   = (const float*)d_in[10];
    const float* prelua = (const float*)d_in[11];
    const float* W_conv = (const float*)d_in[12];
    const float* b_conv = (const float*)d_in[13];
    const float* Wc1    = (const float*)d_in[14];
    const float* bc1    = (const float*)d_in[15];
    const float* Wc2    = (const float*)d_in[16];
    const float* bc2    = (const float*)d_in[17];
    const int* nodelist = (const int*)d_in[18];
    const int* e0       = (const int*)d_in[19];
    const int* e1       = (const int*)d_in[20];
    const int* e2       = (const int*)d_in[21];
    const int* parent1  = (const int*)d_in[22];
    const int* parent2  = (const int*)d_in[23];
    const int* batch1   = (const int*)d_in[24];
    const int* batch2   = (const int*)d_in[25];

    // ---- workspace layout ----
    float* WS  = (float*)d_ws;
    float* ENC = WS;                    // 50000*128; dead after k_gemm2
    int*   DEGS   = (int*)d_ws;                 // 327680
    int*   ROWSTS = DEGS + 327680;              // 327680
    float* DINVS  = (float*)(ROWSTS + 327680);  // 264192
    int*   BSUMS  = (int*)(DINVS + 264192);     // 512
    int*   RANKS  = BSUMS + 512;                // 2350000
    int*   ELISTS = RANKS + 2350000;            // 2350000
    float* U  = WS + 6400000;           // 50000*128
    float* H  = WS + 12800000;          // 50000*128
    float* Y  = WS + 19200000;          // 200000*128
    float* X1 = WS + 44800000;          // 50000*128
    float* X2 = WS + 51200000;          // 12500*128
    float* PL = WS + 52800000;          // 128*384
    float* EDW = WS + 52900000;         // 2100000 per-edge src weights

    hipMemsetAsync(PL, 0, (size_t)128 * 384 * 4, stream);

    // ---- encoder -> ENC; U = prelu(ENC@W_in+b)@W_conv0 (fused) ----
    k_enc3<<<(N_USERS + 63) / 64, 256, 0, stream>>>(
        x_raw, W_des, b_des, W_twe, b_twe, W_num, b_num, W_cat, b_cat, ENC);
    k_gemm2<<<(N_USERS + 31) / 32, 256, 0, stream>>>(
        ENC, W_in, b_in, prelua, W_conv, U, N_USERS);

    // ---- fused CSR builds (+dinv, +edge weights); clobbers ENC (dead) ----
    hipMemsetAsync(DEGS, 0, (size_t)327680 * 4, stream);
    k_count_all<<<(587500 + 255) / 256, 256, 0, stream>>>(
        e0 + EE0, e1 + EE1, e2 + EE2, parent1, parent2, DEGS, RANKS);
    k_scan_all<<<320, 256, 0, stream>>>(DEGS, ROWSTS, BSUMS);
    k_scanadd_all<<<320, 256, 0, stream>>>(ROWSTS, BSUMS, DEGS, DINVS);
    k_scatter_all<<<(587500 + 255) / 256, 256, 0, stream>>>(
        e0, e0 + EE0, e1, e1 + EE1, e2, e2 + EE2, parent1, parent2,
        nodelist, DINVS, ROWSTS, RANKS, ELISTS, EDW);

    // ---- layer 0: GCN over NN0 -> Y; pool -> X1 ----
    k_gatherU<<<(int)(((size_t)NN0 * 32 + 255) / 256), 256, 0, stream>>>(
        U, nodelist, ROWSTS, ELISTS, EDW, DINVS, b_conv, Y, NN0);
    k_poolgather<<<(int)(((size_t)NN1 * 32 + 255) / 256), 256, 0, stream>>>(
        Y, ROWSTS + 264192, ELISTS + 2100000, X1, NN1);

    // ---- layer 1 ----
    k_gemmT<<<(NN1 + 31) / 32, 256, 0, stream>>>(X1, W_conv + 16384, H, NN1);
    k_gather<<<(int)(((size_t)NN1 * 32 + 255) / 256), 256, 0, stream>>>(
        H, ROWSTS + 200704, ELISTS + 1600000, EDW + 1600000, DINVS + 200704,
        b_conv + 128, Y, NN1);
    k_poolgather<<<(int)(((size_t)NN2 * 32 + 255) / 256), 256, 0, stream>>>(
        Y, ROWSTS + 314368, ELISTS + 2300000, X2, NN2);

    // ---- layer 2 ----
    k_gemmT<<<(NN2 + 31) / 32, 256, 0, stream>>>(X2, W_conv + 32768, H, NN2);
    k_gather<<<(int)(((size_t)NN2 * 32 + 255) / 256), 256, 0, stream>>>(
        H, ROWSTS + 250880, ELISTS + 2000000, EDW + 2000000, DINVS + 250880,
        b_conv + 256, Y, NN2);

    // ---- batch pooling (fused, sorted keys) ----
    k_bpool_all<<<587, 128, 0, stream>>>(X1, X2, Y, batch1, batch2, PL);

    // ---- final fused MLP ----
    k_mlp2<<<128, 128, 0, stream>>>(PL, Wc1, bc1, Wc2, bc2, (float*)d_out);
}

// Round 12
// 646.101 us; speedup vs baseline: 1.3135x; 1.1114x over previous
//
#include <hip/hip_runtime.h>

#define N_USERS 50000
#define NN0 200000
#define NN1 50000
#define NN2 12500
#define EE0 1600000
#define EE1 400000
#define EE2 100000

#define ENC_BLOCKS 782     // (50000+63)/64
#define CNT_BLOCKS 2295    // (587500+255)/256
#define GM2_BLOCKS 1563    // (50000+31)/32

// Padded segment geometry (1024 multiples):
// seg:      0:e0        1:e1      2:e2      3:parent1  4:parent2
// deg off:  0           200704    250880    264192     314368   (total 327680)
// scan blk: 196         49        13        49         13       (cum 196,245,258,307,320)
// bsum off: 0           196       245       258        307
// el off:   0           1600000   2000000   2100000    2300000

// ================= K1: encoder (blocks<782) + CSR count (rest) ===============
__global__ __launch_bounds__(256) void k_enc_count(
    const float* __restrict__ xr,
    const float* __restrict__ Wd, const float* __restrict__ bd,
    const float* __restrict__ Wt, const float* __restrict__ bt,
    const float* __restrict__ Wn, const float* __restrict__ bn,
    const float* __restrict__ Wc, const float* __restrict__ bc,
    float* __restrict__ h128,
    const int* __restrict__ d0, const int* __restrict__ d1, const int* __restrict__ d2,
    const int* __restrict__ p1, const int* __restrict__ p2,
    int* __restrict__ degs, int* __restrict__ ranks)
{
    __shared__ float XsB[4368];    // [0,2176): des [k][row]; [2192,4368): tweet
    __shared__ float Ws[32][68];
    __shared__ float xnc[64][8];
    __shared__ float Wl[8][64];

    if (blockIdx.x >= ENC_BLOCKS) {
        // ---------------- CSR count path ----------------
        int t0 = (blockIdx.x - ENC_BLOCKS) * 256 + threadIdx.x;
        if (t0 >= 587500) return;
        #pragma unroll
        for (int k = 0; k < 4; k++) {
            int gid = t0 + k * 587500;
            int idx;
            if (gid < 1600000)      idx = d0[gid];
            else if (gid < 2000000) idx = 200704 + d1[gid - 1600000];
            else if (gid < 2100000) idx = 250880 + d2[gid - 2000000];
            else if (gid < 2300000) idx = 264192 + p1[gid - 2100000];
            else                    idx = 314368 + p2[gid - 2300000];
            ranks[gid] = atomicAdd(&degs[idx], 1);
        }
        return;
    }

    // ---------------- encoder path ----------------
    int t = threadIdx.x;
    int lane = t & 63, wv = t >> 6;
    int cg = t & 15, rg = t >> 4;
    int base = blockIdx.x * 64;

    if (t < 64) {
        int row = base + t;
        if (row < N_USERS) {
            const float* xp = xr + (size_t)row * 1544;
            float4 a = *(const float4*)xp;
            float2 b2 = *(const float2*)(xp + 4);
            float2 c2 = *(const float2*)(xp + 774);
            xnc[t][0] = a.x; xnc[t][1] = a.y; xnc[t][2] = a.z; xnc[t][3] = a.w;
            xnc[t][4] = b2.x; xnc[t][5] = b2.y; xnc[t][6] = c2.x; xnc[t][7] = c2.y;
        } else {
            #pragma unroll
            for (int k = 0; k < 8; k++) xnc[t][k] = 0.f;
        }
    } else if (t >= 192) {
        int l = t - 192;
        #pragma unroll
        for (int k = 0; k < 8; k++) {
            float w = 0.f;
            if (l < 32) { if (k < 6) w = Wn[k * 32 + l]; }
            else        { if (k >= 6) w = Wc[(k - 6) * 32 + (l - 32)]; }
            Wl[k][l] = w;
        }
    }

    int srow = (lane & 15) + wv * 16;
    int grow = base + srow;
    bool vrow = grow < N_USERS;
    const float* xrow = xr + (size_t)grow * 1544;

    float acc[4][4];
    #pragma unroll
    for (int r = 0; r < 4; r++)
        #pragma unroll
        for (int c = 0; c < 4; c++) acc[r][c] = 0.f;

    for (int kc = 0; kc < 768; kc += 32) {
        __syncthreads();
        #pragma unroll
        for (int h = 0; h < 2; h++) {
            int q = (lane >> 4) + h * 4;
            float4 vd = {0.f, 0.f, 0.f, 0.f};
            float2 va = {0.f, 0.f}, vb = {0.f, 0.f};
            if (vrow) {
                const float* xp = xrow + kc + q * 4;
                vd = *(const float4*)(xp + 776);
                va = *(const float2*)(xp + 6);
                vb = *(const float2*)(xp + 8);
            }
            int k0 = q * 4;
            XsB[(k0 + 0) * 68 + srow] = vd.x;
            XsB[(k0 + 1) * 68 + srow] = vd.y;
            XsB[(k0 + 2) * 68 + srow] = vd.z;
            XsB[(k0 + 3) * 68 + srow] = vd.w;
            XsB[2192 + (k0 + 0) * 68 + srow] = va.x;
            XsB[2192 + (k0 + 1) * 68 + srow] = va.y;
            XsB[2192 + (k0 + 2) * 68 + srow] = vb.x;
            XsB[2192 + (k0 + 3) * 68 + srow] = vb.y;
        }
        #pragma unroll
        for (int h = 0; h < 2; h++) {
            int fi = t + h * 256;
            int k = fi >> 4, c4 = (fi & 15) * 4;
            float4 w = (c4 < 32) ? *(const float4*)(Wd + (size_t)(kc + k) * 32 + c4)
                                 : *(const float4*)(Wt + (size_t)(kc + k) * 32 + (c4 - 32));
            *(float4*)&Ws[k][c4] = w;
        }
        __syncthreads();

        const float* Xp = (cg < 8) ? XsB : (XsB + 2192);
        #pragma unroll 8
        for (int k = 0; k < 32; k++) {
            float4 xv = *(const float4*)(Xp + k * 68 + rg * 4);
            float4 wv2 = *(const float4*)&Ws[k][cg * 4];
            acc[0][0] = fmaf(xv.x, wv2.x, acc[0][0]);
            acc[0][1] = fmaf(xv.x, wv2.y, acc[0][1]);
            acc[0][2] = fmaf(xv.x, wv2.z, acc[0][2]);
            acc[0][3] = fmaf(xv.x, wv2.w, acc[0][3]);
            acc[1][0] = fmaf(xv.y, wv2.x, acc[1][0]);
            acc[1][1] = fmaf(xv.y, wv2.y, acc[1][1]);
            acc[1][2] = fmaf(xv.y, wv2.z, acc[1][2]);
            acc[1][3] = fmaf(xv.y, wv2.w, acc[1][3]);
            acc[2][0] = fmaf(xv.z, wv2.x, acc[2][0]);
            acc[2][1] = fmaf(xv.z, wv2.y, acc[2][1]);
            acc[2][2] = fmaf(xv.z, wv2.z, acc[2][2]);
            acc[2][3] = fmaf(xv.z, wv2.w, acc[2][3]);
            acc[3][0] = fmaf(xv.w, wv2.x, acc[3][0]);
            acc[3][1] = fmaf(xv.w, wv2.y, acc[3][1]);
            acc[3][2] = fmaf(xv.w, wv2.z, acc[3][2]);
            acc[3][3] = fmaf(xv.w, wv2.w, acc[3][3]);
        }
    }

    float bh[4], bl[4], wlv[8][4];
    #pragma unroll
    for (int c = 0; c < 4; c++) {
        int j = cg * 4 + c;
        bh[c] = (j < 32) ? bd[j] : bt[j - 32];
        bl[c] = (j < 32) ? bn[j] : bc[j - 32];
        #pragma unroll
        for (int k = 0; k < 8; k++) wlv[k][c] = Wl[k][j];
    }
    #pragma unroll
    for (int r = 0; r < 4; r++) {
        int lr = rg * 4 + r;
        int row = base + lr;
        if (row >= N_USERS) break;
        float4 hv;
        float* ph = &hv.x;
        #pragma unroll
        for (int c = 0; c < 4; c++) {
            float v = acc[r][c] + bh[c];
            ph[c] = v > 0.f ? v : 0.01f * v;
        }
        *(float4*)(h128 + (size_t)row * 128 + cg * 4) = hv;
        float4 lv;
        float* pl = &lv.x;
        #pragma unroll
        for (int c = 0; c < 4; c++) {
            float v = bl[c];
            #pragma unroll
            for (int k = 0; k < 8; k++) v = fmaf(xnc[lr][k], wlv[k][c], v);
            pl[c] = v > 0.f ? v : 0.01f * v;
        }
        *(float4*)(h128 + (size_t)row * 128 + 64 + cg * 4) = lv;
    }
}

// ======== K2: fused dual GEMM (blocks<1563) + atomic-free scatter (rest) =====
__global__ __launch_bounds__(256) void k_gemm2_scatter(
    const float* __restrict__ X, const float* __restrict__ W1,
    const float* __restrict__ b1, const float* __restrict__ pa,
    const float* __restrict__ W2, float* __restrict__ OUT, int n,
    const int* __restrict__ s0, const int* __restrict__ d0,
    const int* __restrict__ s1, const int* __restrict__ d1,
    const int* __restrict__ s2, const int* __restrict__ d2,
    const int* __restrict__ p1, const int* __restrict__ p2,
    const int* __restrict__ nl, const float* __restrict__ dinvs,
    const int* __restrict__ rowsts, const int* __restrict__ ranks,
    int* __restrict__ elists, float* __restrict__ edw)
{
    __shared__ float Xs[32][132];
    __shared__ float Wsh[32][132];

    if (blockIdx.x >= GM2_BLOCKS) {
        // ---------------- scatter path ----------------
        int t0 = (blockIdx.x - GM2_BLOCKS) * 256 + threadIdx.x;
        if (t0 >= 587500) return;
        #pragma unroll
        for (int k = 0; k < 4; k++) {
            int gid = t0 + k * 587500;
            if (gid < 1600000) {
                int s = s0[gid];
                int p = rowsts[d0[gid]] + ranks[gid];
                elists[p] = nl[s];
                edw[p] = dinvs[s];
            } else if (gid < 2000000) {
                int i = gid - 1600000;
                int s = s1[i];
                int p = rowsts[200704 + d1[i]] + ranks[gid];
                elists[1600000 + p] = s;
                edw[1600000 + p] = dinvs[200704 + s];
            } else if (gid < 2100000) {
                int i = gid - 2000000;
                int s = s2[i];
                int p = rowsts[250880 + d2[i]] + ranks[gid];
                elists[2000000 + p] = s;
                edw[2000000 + p] = dinvs[250880 + s];
            } else if (gid < 2300000) {
                int i = gid - 2100000;
                int p = rowsts[264192 + p1[i]] + ranks[gid];
                elists[2100000 + p] = i;
            } else {
                int i = gid - 2300000;
                int p = rowsts[314368 + p2[i]] + ranks[gid];
                elists[2300000 + p] = i;
            }
        }
        return;
    }

    // ---------------- gemm2 path ----------------
    int t = threadIdx.x;
    int cg = t & 31, rg = t >> 5;
    int base = blockIdx.x * 32;

    #pragma unroll
    for (int h = 0; h < 4; h++) {
        int fi = t + h * 256;
        int row = fi >> 5, q = fi & 31;
        float4 v = {0.f, 0.f, 0.f, 0.f};
        if (base + row < n) v = *(const float4*)(X + (size_t)(base + row) * 128 + q * 4);
        *(float4*)&Xs[row][q * 4] = v;
    }

    float acc[4][4];
    #pragma unroll
    for (int r = 0; r < 4; r++)
        #pragma unroll
        for (int c = 0; c < 4; c++) acc[r][c] = 0.f;

    for (int kc = 0; kc < 128; kc += 32) {
        __syncthreads();
        #pragma unroll
        for (int h = 0; h < 4; h++) {
            int fi = t + h * 256;
            int k = fi >> 5, q = fi & 31;
            *(float4*)&Wsh[k][q * 4] = *(const float4*)(W1 + (size_t)(kc + k) * 128 + q * 4);
        }
        __syncthreads();
        #pragma unroll
        for (int k4 = 0; k4 < 8; k4++) {
            int k = k4 * 4;
            float4 w0 = *(const float4*)&Wsh[k + 0][cg * 4];
            float4 w1 = *(const float4*)&Wsh[k + 1][cg * 4];
            float4 w2 = *(const float4*)&Wsh[k + 2][cg * 4];
            float4 w3 = *(const float4*)&Wsh[k + 3][cg * 4];
            #pragma unroll
            for (int r = 0; r < 4; r++) {
                float4 xv = *(const float4*)&Xs[rg * 4 + r][kc + k];
                acc[r][0] = fmaf(xv.w, w3.x, fmaf(xv.z, w2.x, fmaf(xv.y, w1.x, fmaf(xv.x, w0.x, acc[r][0]))));
                acc[r][1] = fmaf(xv.w, w3.y, fmaf(xv.z, w2.y, fmaf(xv.y, w1.y, fmaf(xv.x, w0.y, acc[r][1]))));
                acc[r][2] = fmaf(xv.w, w3.z, fmaf(xv.z, w2.z, fmaf(xv.y, w1.z, fmaf(xv.x, w0.z, acc[r][2]))));
                acc[r][3] = fmaf(xv.w, w3.w, fmaf(xv.z, w2.w, fmaf(xv.y, w1.w, fmaf(xv.x, w0.w, acc[r][3]))));
            }
        }
    }

    float4 bv = *(const float4*)(b1 + cg * 4);
    float4 pv = *(const float4*)(pa + cg * 4);
    __syncthreads();
    #pragma unroll
    for (int r = 0; r < 4; r++) {
        float v0 = acc[r][0] + bv.x; v0 = v0 > 0.f ? v0 : pv.x * v0;
        float v1 = acc[r][1] + bv.y; v1 = v1 > 0.f ? v1 : pv.y * v1;
        float v2 = acc[r][2] + bv.z; v2 = v2 > 0.f ? v2 : pv.z * v2;
        float v3 = acc[r][3] + bv.w; v3 = v3 > 0.f ? v3 : pv.w * v3;
        Xs[rg * 4 + r][cg * 4 + 0] = v0;
        Xs[rg * 4 + r][cg * 4 + 1] = v1;
        Xs[rg * 4 + r][cg * 4 + 2] = v2;
        Xs[rg * 4 + r][cg * 4 + 3] = v3;
        acc[r][0] = 0.f; acc[r][1] = 0.f; acc[r][2] = 0.f; acc[r][3] = 0.f;
    }

    for (int kc = 0; kc < 128; kc += 32) {
        __syncthreads();
        #pragma unroll
        for (int h = 0; h < 4; h++) {
            int fi = t + h * 256;
            int k = fi >> 5, q = fi & 31;
            *(float4*)&Wsh[k][q * 4] = *(const float4*)(W2 + (size_t)(kc + k) * 128 + q * 4);
        }
        __syncthreads();
        #pragma unroll
        for (int k4 = 0; k4 < 8; k4++) {
            int k = k4 * 4;
            float4 w0 = *(const float4*)&Wsh[k + 0][cg * 4];
            float4 w1 = *(const float4*)&Wsh[k + 1][cg * 4];
            float4 w2 = *(const float4*)&Wsh[k + 2][cg * 4];
            float4 w3 = *(const float4*)&Wsh[k + 3][cg * 4];
            #pragma unroll
            for (int r = 0; r < 4; r++) {
                float4 xv = *(const float4*)&Xs[rg * 4 + r][kc + k];
                acc[r][0] = fmaf(xv.w, w3.x, fmaf(xv.z, w2.x, fmaf(xv.y, w1.x, fmaf(xv.x, w0.x, acc[r][0]))));
                acc[r][1] = fmaf(xv.w, w3.y, fmaf(xv.z, w2.y, fmaf(xv.y, w1.y, fmaf(xv.x, w0.y, acc[r][1]))));
                acc[r][2] = fmaf(xv.w, w3.z, fmaf(xv.z, w2.z, fmaf(xv.y, w1.z, fmaf(xv.x, w0.z, acc[r][2]))));
                acc[r][3] = fmaf(xv.w, w3.w, fmaf(xv.z, w2.w, fmaf(xv.y, w1.w, fmaf(xv.x, w0.w, acc[r][3]))));
            }
        }
    }

    #pragma unroll
    for (int r = 0; r < 4; r++) {
        int row = base + rg * 4 + r;
        if (row >= n) break;
        float4 v;
        v.x = acc[r][0]; v.y = acc[r][1]; v.z = acc[r][2]; v.w = acc[r][3];
        *(float4*)(OUT + (size_t)row * 128 + cg * 4) = v;
    }
}

// ---------------- [n,128] @ [128,128] GEMM, 4x4 register tile ----------------
__global__ __launch_bounds__(256) void k_gemmT(
    const float* X, const float* __restrict__ W, float* OUT, int n)
{
    __shared__ float Xs[32][132];
    __shared__ float Ws[32][132];
    int t = threadIdx.x;
    int cg = t & 31, rg = t >> 5;
    int base = blockIdx.x * 32;

    #pragma unroll
    for (int h = 0; h < 4; h++) {
        int fi = t + h * 256;
        int row = fi >> 5, q = fi & 31;
        float4 v = {0.f, 0.f, 0.f, 0.f};
        if (base + row < n) v = *(const float4*)(X + (size_t)(base + row) * 128 + q * 4);
        *(float4*)&Xs[row][q * 4] = v;
    }

    float acc[4][4];
    #pragma unroll
    for (int r = 0; r < 4; r++)
        #pragma unroll
        for (int c = 0; c < 4; c++) acc[r][c] = 0.f;

    for (int kc = 0; kc < 128; kc += 32) {
        __syncthreads();
        #pragma unroll
        for (int h = 0; h < 4; h++) {
            int fi = t + h * 256;
            int k = fi >> 5, q = fi & 31;
            *(float4*)&Ws[k][q * 4] = *(const float4*)(W + (size_t)(kc + k) * 128 + q * 4);
        }
        __syncthreads();
        #pragma unroll
        for (int k4 = 0; k4 < 8; k4++) {
            int k = k4 * 4;
            float4 w0 = *(const float4*)&Ws[k + 0][cg * 4];
            float4 w1 = *(const float4*)&Ws[k + 1][cg * 4];
            float4 w2 = *(const float4*)&Ws[k + 2][cg * 4];
            float4 w3 = *(const float4*)&Ws[k + 3][cg * 4];
            #pragma unroll
            for (int r = 0; r < 4; r++) {
                float4 xv = *(const float4*)&Xs[rg * 4 + r][kc + k];
                acc[r][0] = fmaf(xv.w, w3.x, fmaf(xv.z, w2.x, fmaf(xv.y, w1.x, fmaf(xv.x, w0.x, acc[r][0]))));
                acc[r][1] = fmaf(xv.w, w3.y, fmaf(xv.z, w2.y, fmaf(xv.y, w1.y, fmaf(xv.x, w0.y, acc[r][1]))));
                acc[r][2] = fmaf(xv.w, w3.z, fmaf(xv.z, w2.z, fmaf(xv.y, w1.z, fmaf(xv.x, w0.z, acc[r][2]))));
                acc[r][3] = fmaf(xv.w, w3.w, fmaf(xv.z, w2.w, fmaf(xv.y, w1.w, fmaf(xv.x, w0.w, acc[r][3]))));
            }
        }
    }

    #pragma unroll
    for (int r = 0; r < 4; r++) {
        int row = base + rg * 4 + r;
        if (row >= n) break;
        float4 v;
        v.x = acc[r][0]; v.y = acc[r][1]; v.z = acc[r][2]; v.w = acc[r][3];
        *(float4*)(OUT + (size_t)row * 128 + cg * 4) = v;
    }
}

// ---------------- scan kernels ----------------------------------------------
__device__ __forceinline__ void seg_of_scanblk(int b, int& doff, int& bsoff, int& lb) {
    if (b < 196)      { doff = 0;      bsoff = 0;   lb = b; }
    else if (b < 245) { doff = 200704; bsoff = 196; lb = b - 196; }
    else if (b < 258) { doff = 250880; bsoff = 245; lb = b - 245; }
    else if (b < 307) { doff = 264192; bsoff = 258; lb = b - 258; }
    else              { doff = 314368; bsoff = 307; lb = b - 307; }
}

__global__ __launch_bounds__(256) void k_scan_all(
    const int* __restrict__ degs, int* __restrict__ rowsts, int* __restrict__ bsums)
{
    __shared__ int sh[256];
    int doff, bsoff, lb;
    seg_of_scanblk(blockIdx.x, doff, bsoff, lb);
    int t = threadIdx.x;
    int base = doff + lb * 1024 + t * 4;
    int v[4], s = 0;
    #pragma unroll
    for (int k = 0; k < 4; k++) { v[k] = degs[base + k]; s += v[k]; }
    sh[t] = s;
    __syncthreads();
    for (int off = 1; off < 256; off <<= 1) {
        int x = 0;
        if (t >= off) x = sh[t - off];
        __syncthreads();
        if (t >= off) sh[t] += x;
        __syncthreads();
    }
    int ex = sh[t] - s;
    if (t == 255) bsums[bsoff + lb] = sh[255];
    #pragma unroll
    for (int k = 0; k < 4; k++) { rowsts[base + k] = ex; ex += v[k]; }
}

__global__ __launch_bounds__(256) void k_scanadd_all(
    int* __restrict__ rowsts, const int* __restrict__ bsums,
    const int* __restrict__ degs, float* __restrict__ dinvs)
{
    __shared__ int sh[256];
    int doff, bsoff, lb;
    seg_of_scanblk(blockIdx.x, doff, bsoff, lb);
    int t = threadIdx.x;
    sh[t] = (t < lb) ? bsums[bsoff + t] : 0;
    __syncthreads();
    #pragma unroll
    for (int off = 128; off >= 1; off >>= 1) {
        if (t < off) sh[t] += sh[t + off];
        __syncthreads();
    }
    int add = sh[0];
    int base = doff + lb * 1024 + t * 4;
    bool dodinv = (doff <= 250880);
    #pragma unroll
    for (int k = 0; k < 4; k++) {
        int i = base + k;
        rowsts[i] += add;
        if (dodinv) dinvs[i] = rsqrtf((float)degs[i] + 1.0f);
    }
}

// ---------------- GCN gathers (permuted output for fused-seq pooling) --------
// L0: process i in parent-CSR child order; d = perm[i]; write out[i]
__global__ __launch_bounds__(256) void k_gatherU_perm(
    const float* __restrict__ U, const int* __restrict__ nl,
    const int* __restrict__ rowst, const int* __restrict__ elist,
    const float* __restrict__ edw, const float* __restrict__ dinv,
    const float* __restrict__ bias, const int* __restrict__ perm,
    float* __restrict__ out, int n)
{
    size_t gid = (size_t)blockIdx.x * 256 + threadIdx.x;
    int i = (int)(gid >> 5);
    if (i >= n) return;
    int l = (int)(gid & 31);
    int d = perm[i];
    const float4* Uv = (const float4*)U;
    float dd = dinv[d];
    float4 self = Uv[(size_t)nl[d] * 32 + l];
    float4 acc;
    acc.x = self.x * dd; acc.y = self.y * dd; acc.z = self.z * dd; acc.w = self.w * dd;
    int s0 = rowst[d], s1 = rowst[d + 1];
    for (int e = s0; e < s1; ++e) {
        int srow = elist[e];
        float w = edw[e];
        float4 v = Uv[(size_t)srow * 32 + l];
        acc.x = fmaf(v.x, w, acc.x);
        acc.y = fmaf(v.y, w, acc.y);
        acc.z = fmaf(v.z, w, acc.z);
        acc.w = fmaf(v.w, w, acc.w);
    }
    const float4 b = ((const float4*)bias)[l];
    float4 y;
    y.x = fmaxf(fmaf(acc.x, dd, b.x), 0.f);
    y.y = fmaxf(fmaf(acc.y, dd, b.y), 0.f);
    y.z = fmaxf(fmaf(acc.z, dd, b.z), 0.f);
    y.w = fmaxf(fmaf(acc.w, dd, b.w), 0.f);
    ((float4*)out)[(size_t)i * 32 + l] = y;
}

// L1/L2: perm!=null -> d=perm[i], out[i]; perm==null -> d=i, out[d]
__global__ __launch_bounds__(256) void k_gather_perm(
    const float* __restrict__ h, const int* __restrict__ rowst,
    const int* __restrict__ elist, const float* __restrict__ edw,
    const float* __restrict__ dinv, const float* __restrict__ bias,
    const int* __restrict__ perm, float* __restrict__ out, int n)
{
    size_t gid = (size_t)blockIdx.x * 256 + threadIdx.x;
    int i = (int)(gid >> 5);
    if (i >= n) return;
    int l = (int)(gid & 31);
    int d = perm ? perm[i] : i;
    const float4* hv = (const float4*)h;
    float dd = dinv[d];
    float4 self = hv[(size_t)d * 32 + l];
    float4 acc;
    acc.x = self.x * dd; acc.y = self.y * dd; acc.z = self.z * dd; acc.w = self.w * dd;
    int s0 = rowst[d], s1 = rowst[d + 1];
    for (int e = s0; e < s1; ++e) {
        int srow = elist[e];
        float w = edw[e];
        float4 v = hv[(size_t)srow * 32 + l];
        acc.x = fmaf(v.x, w, acc.x);
        acc.y = fmaf(v.y, w, acc.y);
        acc.z = fmaf(v.z, w, acc.z);
        acc.w = fmaf(v.w, w, acc.w);
    }
    const float4 b = ((const float4*)bias)[l];
    float4 y;
    y.x = fmaxf(fmaf(acc.x, dd, b.x), 0.f);
    y.y = fmaxf(fmaf(acc.y, dd, b.y), 0.f);
    y.z = fmaxf(fmaf(acc.z, dd, b.z), 0.f);
    y.w = fmaxf(fmaf(acc.w, dd, b.w), 0.f);
    ((float4*)out)[(size_t)i * 32 + l] = y;
}

// sequential-range pool: out[p] = relu(sum Yp[prowst[p]..prowst[p+1]))
__global__ __launch_bounds__(256) void k_poolseq(
    const float* __restrict__ Yp, const int* __restrict__ prowst,
    float* __restrict__ out, int np)
{
    size_t gid = (size_t)blockIdx.x * 256 + threadIdx.x;
    int p = (int)(gid >> 5);
    if (p >= np) return;
    int l = (int)(gid & 31);
    const float4* yv = (const float4*)Yp;
    float4 acc = {0.f, 0.f, 0.f, 0.f};
    int c0 = prowst[p], c1 = prowst[p + 1];
    for (int c = c0; c < c1; ++c) {
        float4 v = yv[(size_t)c * 32 + l];
        acc.x += v.x; acc.y += v.y; acc.z += v.z; acc.w += v.w;
    }
    float4 y;
    y.x = fmaxf(acc.x, 0.f); y.y = fmaxf(acc.y, 0.f);
    y.z = fmaxf(acc.z, 0.f); y.w = fmaxf(acc.w, 0.f);
    ((float4*)out)[(size_t)p * 32 + l] = y;
}

__global__ __launch_bounds__(128) void k_bpool_all(
    const float* __restrict__ X1, const float* __restrict__ X2, const float* __restrict__ Y2,
    const int* __restrict__ b1, const int* __restrict__ b2, float* __restrict__ pl)
{
    int b = blockIdx.x;
    const float* src; const int* bidx; int coloff, n, r0;
    if (b < 391)      { src = X1; bidx = b1; coloff = 0;   n = 50000; r0 = b * 128; }
    else if (b < 489) { src = X2; bidx = b2; coloff = 128; n = 12500; r0 = (b - 391) * 128; }
    else              { src = Y2; bidx = b2; coloff = 256; n = 12500; r0 = (b - 489) * 128; }
    if (r0 >= n) return;
    int j = threadIdx.x;
    int r1 = min(r0 + 128, n);
    float acc = 0.f;
    int prev = bidx[r0];
    for (int r = r0; r < r1; ++r) {
        int bb = bidx[r];
        if (bb != prev) {
            unsafeAtomicAdd(&pl[(size_t)prev * 384 + coloff + j], acc);
            acc = 0.f; prev = bb;
        }
        acc += src[(size_t)r * 128 + j];
    }
    unsafeAtomicAdd(&pl[(size_t)prev * 384 + coloff + j], acc);
}

__global__ void k_mlp2(const float* __restrict__ PL,
                       const float* __restrict__ Wc1, const float* __restrict__ bc1,
                       const float* __restrict__ Wc2, const float* __restrict__ bc2,
                       float* __restrict__ out)
{
    __shared__ float as[384];
    __shared__ float zs[128];
    int r = blockIdx.x, j = threadIdx.x;
    as[j] = PL[(size_t)r * 384 + j];
    as[j + 128] = PL[(size_t)r * 384 + 128 + j];
    as[j + 256] = PL[(size_t)r * 384 + 256 + j];
    __syncthreads();
    float acc = bc1[j];
    for (int k = 0; k < 384; k++) acc = fmaf(as[k], Wc1[(size_t)k * 128 + j], acc);
    zs[j] = fmaxf(acc, 0.f);
    __syncthreads();
    float o = bc2[j];
    for (int k = 0; k < 128; k++) o = fmaf(zs[k], Wc2[(size_t)k * 128 + j], o);
    out[(size_t)r * 128 + j] = o;
}

extern "C" void kernel_launch(void* const* d_in, const int* in_sizes, int n_in,
                              void* d_out, int out_size, void* d_ws, size_t ws_size,
                              hipStream_t stream)
{
    const float* x_raw  = (const float*)d_in[0];
    const float* W_des  = (const float*)d_in[1];
    const float* b_des  = (const float*)d_in[2];
    const float* W_twe  = (const float*)d_in[3];
    const float* b_twe  = (const float*)d_in[4];
    const float* W_num  = (const float*)d_in[5];
    const float* b_num  = (const float*)d_in[6];
    const float* W_cat  = (const float*)d_in[7];
    const float* b_cat  = (const float*)d_in[8];
    const float* W_in   = (const float*)d_in[9];
    const float* b_in   = (const float*)d_in[10];
    const float* prelua = (const float*)d_in[11];
    const float* W_conv = (const float*)d_in[12];
    const float* b_conv = (const float*)d_in[13];
    const float* Wc1    = (const float*)d_in[14];
    const float* bc1    = (const float*)d_in[15];
    const float* Wc2    = (const float*)d_in[16];
    const float* bc2    = (const float*)d_in[17];
    const int* nodelist = (const int*)d_in[18];
    const int* e0       = (const int*)d_in[19];
    const int* e1       = (const int*)d_in[20];
    const int* e2       = (const int*)d_in[21];
    const int* parent1  = (const int*)d_in[22];
    const int* parent2  = (const int*)d_in[23];
    const int* batch1   = (const int*)d_in[24];
    const int* batch2   = (const int*)d_in[25];

    // ---- workspace layout (243 MB; CSR scratch no longer aliases ENC) ----
    float* WS  = (float*)d_ws;
    float* ENC = WS;                    // 50000*128
    float* U   = WS + 6400000;          // 50000*128
    float* H   = WS + 12800000;         // 50000*128
    float* Y   = WS + 19200000;         // 200000*128 (permuted L0 out; reused L1/L2)
    float* X1  = WS + 44800000;         // 50000*128
    float* X2  = WS + 51200000;         // 12500*128
    float* PL  = WS + 52800000;         // 128*384
    float* EDW = WS + 52900000;         // 2100000
    int*   DEGS   = (int*)(WS + 55000000);      // 327680
    int*   ROWSTS = DEGS + 327680;              // 327680
    float* DINVS  = (float*)(ROWSTS + 327680);  // 264192
    int*   BSUMS  = (int*)(DINVS + 264192);     // 512
    int*   RANKS  = BSUMS + 512;                // 2350000
    int*   ELISTS = RANKS + 2350000;            // 2350000

    hipMemsetAsync(PL, 0, (size_t)128 * 384 * 4, stream);
    hipMemsetAsync(DEGS, 0, (size_t)327680 * 4, stream);

    // ---- K1: encoder || CSR count (independent work, one launch) ----
    k_enc_count<<<ENC_BLOCKS + CNT_BLOCKS, 256, 0, stream>>>(
        x_raw, W_des, b_des, W_twe, b_twe, W_num, b_num, W_cat, b_cat, ENC,
        e0 + EE0, e1 + EE1, e2 + EE2, parent1, parent2, DEGS, RANKS);

    // ---- scans ----
    k_scan_all<<<320, 256, 0, stream>>>(DEGS, ROWSTS, BSUMS);
    k_scanadd_all<<<320, 256, 0, stream>>>(ROWSTS, BSUMS, DEGS, DINVS);

    // ---- K2: dual GEMM (U) || atomic-free scatter ----
    k_gemm2_scatter<<<GM2_BLOCKS + CNT_BLOCKS, 256, 0, stream>>>(
        ENC, W_in, b_in, prelua, W_conv, U, N_USERS,
        e0, e0 + EE0, e1, e1 + EE1, e2, e2 + EE2, parent1, parent2,
        nodelist, DINVS, ROWSTS, RANKS, ELISTS, EDW);

    // ---- layer 0: GCN in parent-child order -> Y (permuted); seq pool -> X1 --
    k_gatherU_perm<<<(int)(((size_t)NN0 * 32 + 255) / 256), 256, 0, stream>>>(
        U, nodelist, ROWSTS, ELISTS, EDW, DINVS, b_conv,
        ELISTS + 2100000, Y, NN0);
    k_poolseq<<<(int)(((size_t)NN1 * 32 + 255) / 256), 256, 0, stream>>>(
        Y, ROWSTS + 264192, X1, NN1);

    // ---- layer 1 ----
    k_gemmT<<<(NN1 + 31) / 32, 256, 0, stream>>>(X1, W_conv + 16384, H, NN1);
    k_gather_perm<<<(int)(((size_t)NN1 * 32 + 255) / 256), 256, 0, stream>>>(
        H, ROWSTS + 200704, ELISTS + 1600000, EDW + 1600000, DINVS + 200704,
        b_conv + 128, ELISTS + 2300000, Y, NN1);
    k_poolseq<<<(int)(((size_t)NN2 * 32 + 255) / 256), 256, 0, stream>>>(
        Y, ROWSTS + 314368, X2, NN2);

    // ---- layer 2 (plain order for bpool) ----
    k_gemmT<<<(NN2 + 31) / 32, 256, 0, stream>>>(X2, W_conv + 32768, H, NN2);
    k_gather_perm<<<(int)(((size_t)NN2 * 32 + 255) / 256), 256, 0, stream>>>(
        H, ROWSTS + 250880, ELISTS + 2000000, EDW + 2000000, DINVS + 250880,
        b_conv + 256, nullptr, Y, NN2);

    // ---- batch pooling (fused, sorted keys) ----
    k_bpool_all<<<587, 128, 0, stream>>>(X1, X2, Y, batch1, batch2, PL);

    // ---- final fused MLP ----
    k_mlp2<<<128, 128, 0, stream>>>(PL, Wc1, bc1, Wc2, bc2, (float*)d_out);
}